// Round 3
// baseline (328.773 us; speedup 1.0000x reference)
//
#include <hip/hip_runtime.h>
#include <hip/hip_bf16.h>
#include <math.h>

#define N_B 2
#define C_CH 256
#define HW_SZ 4096
#define CL_CH 16

typedef __bf16 bf16x8 __attribute__((ext_vector_type(8)));
typedef float f32x4 __attribute__((ext_vector_type(4)));

__device__ __forceinline__ unsigned short f2bf(float x){
  __hip_bfloat16 b = __float2bfloat16(x);   // RTNE
  return *reinterpret_cast<unsigned short*>(&b);
}
__device__ __forceinline__ unsigned int pack_bf2(float a, float b){
  return (unsigned int)f2bf(a) | ((unsigned int)f2bf(b) << 16);
}
// tanh, NaN-safe: 1 - 2/(1+e^{2x})
__device__ __forceinline__ float tanh_fast(float x){
  float e = __expf(2.0f * x);
  return 1.0f - 2.0f / (1.0f + e);
}

// ---------- Stage-1 conv (C->1)
__global__ void k_conv1(const float* __restrict__ f1, const float* __restrict__ f2,
                        const float* __restrict__ w1, const float* __restrict__ w2,
                        const float* __restrict__ b1, const float* __restrict__ b2,
                        float* __restrict__ cv){
  const int i = blockIdx.z, n = blockIdx.y, t = threadIdx.x;
  const int ql = t & 63, cg = t >> 6;
  const int q = blockIdx.x * 64 + ql;
  const float* f = (i ? f2 : f1) + n * C_CH * HW_SZ;
  const float* w = i ? w2 : w1;
  __shared__ float ws[C_CH];
  __shared__ float red[4][72];
  ws[t] = w[t];
  __syncthreads();
  float acc = 0.f;
  #pragma unroll 8
  for (int c = cg * 64; c < cg * 64 + 64; ++c)
    acc += f[c * HW_SZ + q] * ws[c];
  red[cg][ql] = acc;
  __syncthreads();
  if (t < 64){
    float s = red[0][t] + red[1][t] + red[2][t] + red[3][t] + (i ? b2[0] : b1[0]);
    cv[(i * 2 + n) * HW_SZ + blockIdx.x * 64 + t] = s;
  }
}

// ---------- softmax over 4096 per row; grid(4) block 256
__global__ void k_softmax(const float* __restrict__ cv, float* __restrict__ pr){
  const int r = blockIdx.x, t = threadIdx.x;
  const float* x = cv + r * HW_SZ;
  float* y = pr + r * HW_SZ;
  __shared__ float red[256];
  float v[16];
  float m = -1e30f;
  #pragma unroll
  for (int j = 0; j < 16; j++){ v[j] = x[j * 256 + t]; m = fmaxf(m, v[j]); }
  red[t] = m; __syncthreads();
  for (int s = 128; s > 0; s >>= 1){ if (t < s) red[t] = fmaxf(red[t], red[t + s]); __syncthreads(); }
  m = red[0]; __syncthreads();
  float sum = 0.f;
  #pragma unroll
  for (int j = 0; j < 16; j++){ v[j] = __expf(v[j] - m); sum += v[j]; }
  red[t] = sum; __syncthreads();
  for (int s = 128; s > 0; s >>= 1){ if (t < s) red[t] += red[t + s]; __syncthreads(); }
  const float inv = 1.0f / red[0];
  #pragma unroll
  for (int j = 0; j < 16; j++) y[j * 256 + t] = v[j] * inv;
}

// ---------- fs_i = bf16(pr_i * f_i) ; clT_i[q][k] = bf16(pw_i @ (pr*f) + pb_i)
__global__ void k_scale_cl(const float* __restrict__ f1, const float* __restrict__ f2,
                           const float* __restrict__ pr,
                           const float* __restrict__ pw1, const float* __restrict__ pw2,
                           const float* __restrict__ pb1, const float* __restrict__ pb2,
                           unsigned short* __restrict__ fs1, unsigned short* __restrict__ fs2,
                           unsigned short* __restrict__ clT1, unsigned short* __restrict__ clT2){
  const int i = blockIdx.z, n = blockIdx.y, t = threadIdx.x;
  const int ql = t & 63, cg = t >> 6;
  const int q = blockIdx.x * 64 + ql;
  const float* f = (i ? f2 : f1) + n * C_CH * HW_SZ;
  unsigned short* fs = (i ? fs2 : fs1) + n * C_CH * HW_SZ;
  unsigned short* clT = (i ? clT2 : clT1) + n * CL_CH * HW_SZ;
  const float* pw = i ? pw2 : pw1;
  const float* pb = i ? pb2 : pb1;
  __shared__ float wls[CL_CH * C_CH];
  __shared__ float red[4][CL_CH][66];
  #pragma unroll
  for (int j = 0; j < 16; j++) wls[j * 256 + t] = pw[j * 256 + t];
  __syncthreads();
  const float p = pr[(i * 2 + n) * HW_SZ + q];
  float acc[16];
  #pragma unroll
  for (int k = 0; k < 16; k++) acc[k] = 0.f;
  for (int c = cg * 64; c < cg * 64 + 64; ++c){
    float vv = f[c * HW_SZ + q] * p;
    fs[c * HW_SZ + q] = f2bf(vv);
    #pragma unroll
    for (int k = 0; k < 16; k++) acc[k] += wls[k * 256 + c] * vv;
  }
  #pragma unroll
  for (int k = 0; k < 16; k++) red[cg][k][ql] = acc[k];
  __syncthreads();
  #pragma unroll
  for (int j = 0; j < 4; j++){
    int e = j * 256 + t; int k = e >> 6, qq = e & 63;
    float s = red[0][k][qq] + red[1][k][qq] + red[2][k][qq] + red[3][k][qq] + pb[k];
    clT[(blockIdx.x * 64 + qq) * CL_CH + k] = f2bf(s);
  }
}

// ---------- fused hat GEMM via MFMA, software-pipelined, XOR-swizzled LDS.
// out[c,q] = sum_p fs[c,p] * tanh(sum_k v[k,p]*u[k,q])
// grid(128 qtiles of 32, 2 c-halves of 128, 4 n*i), block 256 (4 waves).
__global__ __launch_bounds__(256, 4) void k_hat(
    const unsigned short* __restrict__ fs1, const unsigned short* __restrict__ fs2,
    const unsigned short* __restrict__ clT1, const unsigned short* __restrict__ clT2,
    float* __restrict__ hat1, float* __restrict__ hat2){
  const int t = threadIdx.x;
  const int ni = blockIdx.z, n = ni & 1, i = ni >> 1;
  const int c0 = blockIdx.y * 128;
  const int q0 = blockIdx.x * 32;
  const unsigned short* fs = (i ? fs2 : fs1) + n * C_CH * HW_SZ;
  const unsigned short* uT = (i ? clT1 : clT2) + n * CL_CH * HW_SZ;  // q-side [HW][16]
  const unsigned short* vT = (i ? clT2 : clT1) + n * CL_CH * HW_SZ;  // p-side [HW][16]
  float* out = (i ? hat2 : hat1) + n * C_CH * HW_SZ;

  __shared__ __align__(16) unsigned short fsLs[128 * 64];  // fs tile [c][p], XOR-swizzled 16B chunks
  __shared__ __align__(16) unsigned short aLs[32 * 64];    // a tile  [q][p], XOR-swizzled
  __shared__ __align__(16) unsigned short vLs[64 * 40];    // vT tile [p][k], k>=16 zero

  const int lane = t & 63, w = t >> 6;
  const int g = lane >> 4, lr = lane & 15;

  // zero-pad vLs k in [16,32)
  #pragma unroll
  for (int e = t; e < 512; e += 256){
    int p = e >> 3, kk = 16 + (e & 7) * 2;
    *reinterpret_cast<unsigned int*>(&vLs[p * 40 + kk]) = 0u;
  }

  // one-time u fragments in registers (zeros for k>=16)
  bf16x8 ubop[2];
  #pragma unroll
  for (int qf = 0; qf < 2; ++qf){
    if (g < 2)
      ubop[qf] = *reinterpret_cast<const bf16x8*>(&uT[(q0 + qf * 16 + lr) * CL_CH + g * 8]);
    else {
      bf16x8 z;
      #pragma unroll
      for (int j = 0; j < 8; j++) z[j] = (__bf16)0.0f;
      ubop[qf] = z;
    }
  }

  f32x4 acc[2][2];
  #pragma unroll
  for (int cf = 0; cf < 2; ++cf)
    #pragma unroll
    for (int qf = 0; qf < 2; ++qf) acc[cf][qf] = (f32x4){0.f, 0.f, 0.f, 0.f};
  const f32x4 zz = {0.f, 0.f, 0.f, 0.f};

  const int scl = t >> 3, sjb = t & 7;        // fs staging coords (4 rows per it)
  const int svp = t >> 1, svh = t & 1;        // vT staging coords (t<128)

  // prologue loads (chunk 0)
  uint4 freg[4]; uint4 vreg;
  #pragma unroll
  for (int it = 0; it < 4; ++it)
    freg[it] = *reinterpret_cast<const uint4*>(&fs[(c0 + it * 32 + scl) * HW_SZ + sjb * 8]);
  if (t < 128) vreg = *reinterpret_cast<const uint4*>(&vT[svp * CL_CH + svh * 8]);

  for (int p0 = 0; p0 < HW_SZ; p0 += 64){
    const int p0n = (p0 + 64) & (HW_SZ - 1);   // wrap: avoids branch, reads valid mem
    __syncthreads();  // prev chunk's LDS readers done
    // write staged tiles
    #pragma unroll
    for (int it = 0; it < 4; ++it){
      int cl = it * 32 + scl;
      *reinterpret_cast<uint4*>(&fsLs[cl * 64 + ((sjb ^ (cl & 7)) * 8)]) = freg[it];
    }
    if (t < 128) *reinterpret_cast<uint4*>(&vLs[svp * 40 + svh * 8]) = vreg;
    // issue next chunk's loads (latency hides under d-gen + main MFMA)
    #pragma unroll
    for (int it = 0; it < 4; ++it)
      freg[it] = *reinterpret_cast<const uint4*>(&fs[(c0 + it * 32 + scl) * HW_SZ + p0n + sjb * 8]);
    if (t < 128) vreg = *reinterpret_cast<const uint4*>(&vT[(p0n + svp) * CL_CH + svh * 8]);
    __syncthreads();  // tiles visible

    // ---- d-gen: wave w covers p-range [w*16, w*16+16), q 0..31
    {
      bf16x8 aop = *reinterpret_cast<const bf16x8*>(&vLs[(w * 16 + lr) * 40 + g * 8]);
      #pragma unroll
      for (int qf = 0; qf < 2; ++qf){
        f32x4 dv = __builtin_amdgcn_mfma_f32_16x16x32_bf16(aop, ubop[qf], zz, 0, 0, 0);
        unsigned int lo = pack_bf2(tanh_fast(dv[0]), tanh_fast(dv[1]));
        unsigned int hi = pack_bf2(tanh_fast(dv[2]), tanh_fast(dv[3]));
        // lane holds a[q = qf*16+lr][p = w*16 + 4g + r]
        int q = qf * 16 + lr;
        int chunk = w * 2 + (g >> 1);           // 16B-chunk = p/8
        uint2 pk = {lo, hi};
        *reinterpret_cast<uint2*>(&aLs[q * 64 + ((chunk ^ (q & 7)) * 8) + (g & 1) * 4]) = pk;
      }
    }
    __syncthreads();  // a tile visible

    // ---- main MFMA: D[c][q] += fs[c][p] * a[q][p]
    #pragma unroll
    for (int ks = 0; ks < 2; ++ks){
      bf16x8 af[2], bq[2];
      #pragma unroll
      for (int cf = 0; cf < 2; ++cf){
        int row = w * 32 + cf * 16 + lr;
        af[cf] = *reinterpret_cast<const bf16x8*>(&fsLs[row * 64 + (((ks * 4 + g) ^ (row & 7)) * 8)]);
      }
      #pragma unroll
      for (int qf = 0; qf < 2; ++qf){
        int qrow = qf * 16 + lr;
        bq[qf] = *reinterpret_cast<const bf16x8*>(&aLs[qrow * 64 + (((ks * 4 + g) ^ (qrow & 7)) * 8)]);
      }
      #pragma unroll
      for (int cf = 0; cf < 2; ++cf)
        #pragma unroll
        for (int qf = 0; qf < 2; ++qf)
          acc[cf][qf] = __builtin_amdgcn_mfma_f32_16x16x32_bf16(af[cf], bq[qf], acc[cf][qf], 0, 0, 0);
    }
  }

  // ---- store: lane holds D[c = base + 4g + r][q = base + lr]
  #pragma unroll
  for (int cf = 0; cf < 2; ++cf)
    #pragma unroll
    for (int qf = 0; qf < 2; ++qf){
      #pragma unroll
      for (int r = 0; r < 4; ++r){
        int c = c0 + w * 32 + cf * 16 + g * 4 + r;
        int q = q0 + qf * 16 + lr;
        out[c * HW_SZ + q] = acc[cf][qf][r];
      }
    }
}

// ---------- l2norm(channels) + residual + relu (IN-PLACE into hat) + stage-2 conv
__global__ void k_norm(float* __restrict__ hat1, float* __restrict__ hat2,
                       const float* __restrict__ f1, const float* __restrict__ f2,
                       const float* __restrict__ cw1, const float* __restrict__ cw2,
                       const float* __restrict__ cb1, const float* __restrict__ cb2,
                       float* __restrict__ cv2){
  const int i = blockIdx.z, n = blockIdx.y, t = threadIdx.x;
  const int ql = t & 63, cg = t >> 6;
  const int q = blockIdx.x * 64 + ql;
  float* hat = (i ? hat2 : hat1) + n * C_CH * HW_SZ;
  const float* f = (i ? f2 : f1) + n * C_CH * HW_SZ;
  __shared__ float ws[C_CH];
  __shared__ float red[4][72];
  __shared__ float invs[64];
  ws[t] = (i ? cw2 : cw1)[t];
  __syncthreads();
  float s = 0.f;
  #pragma unroll 8
  for (int c = cg * 64; c < cg * 64 + 64; ++c){ float h = hat[c * HW_SZ + q]; s += h * h; }
  red[cg][ql] = s; __syncthreads();
  if (t < 64){
    float ss = red[0][t] + red[1][t] + red[2][t] + red[3][t];
    invs[t] = 1.0f / fmaxf(sqrtf(ss), 1e-12f);
  }
  __syncthreads();
  const float inv = invs[ql];
  float ca = 0.f;
  #pragma unroll 8
  for (int c = cg * 64; c < cg * 64 + 64; ++c){
    float vv = fmaxf(hat[c * HW_SZ + q] * inv + f[c * HW_SZ + q], 0.0f);
    hat[c * HW_SZ + q] = vv;  // in-place: only this thread touches [c][q]
    ca += ws[c] * vv;
  }
  red[cg][ql] = ca; __syncthreads();
  if (t < 64){
    float ss = red[0][t] + red[1][t] + red[2][t] + red[3][t] + (i ? cb2[0] : cb1[0]);
    cv2[(i * 2 + n) * HW_SZ + blockIdx.x * 64 + t] = ss;
  }
}

// ---------- final: out_i = pr2_i * fp_i
__global__ void k_final(const float* __restrict__ fp1, const float* __restrict__ fp2,
                        const float* __restrict__ pr2, float* __restrict__ outp){
  const int i = blockIdx.z;
  const int idx4 = (blockIdx.x * 256 + threadIdx.x) * 4;
  const int n = idx4 >> 20;
  const int q = idx4 & (HW_SZ - 1);
  const float* fp = i ? fp2 : fp1;
  float4 vv = *reinterpret_cast<const float4*>(&fp[idx4]);
  float4 pp = *reinterpret_cast<const float4*>(&pr2[(i * 2 + n) * HW_SZ + q]);
  float4 o; o.x = vv.x * pp.x; o.y = vv.y * pp.y; o.z = vv.z * pp.z; o.w = vv.w * pp.w;
  *reinterpret_cast<float4*>(&outp[i * (C_CH * HW_SZ * N_B) + idx4]) = o;
}

extern "C" void kernel_launch(void* const* d_in, const int* in_sizes, int n_in,
                              void* d_out, int out_size, void* d_ws, size_t ws_size,
                              hipStream_t stream){
  const float* f1  = (const float*)d_in[0];
  const float* f2  = (const float*)d_in[1];
  const float* pw1 = (const float*)d_in[2];
  const float* pb1 = (const float*)d_in[3];
  const float* pw2 = (const float*)d_in[4];
  const float* pb2 = (const float*)d_in[5];
  const float* cw1 = (const float*)d_in[6];
  const float* cb1 = (const float*)d_in[7];
  const float* cw2 = (const float*)d_in[8];
  const float* cb2 = (const float*)d_in[9];
  float* ws = (float*)d_ws;
  // layout (float offsets): HAT doubles as FP (k_norm in-place, k_final reads it)
  float* HAT1 = ws;                                        // 2,097,152 floats
  float* HAT2 = ws + 2097152;
  unsigned short* FS1 = (unsigned short*)(ws + 4194304);   // bf16 [C][HW] per n
  unsigned short* FS2 = (unsigned short*)(ws + 5242880);
  unsigned short* CLT1 = (unsigned short*)(ws + 6291456);  // bf16 [HW][16] per n (65,536 floats)
  unsigned short* CLT2 = (unsigned short*)(ws + 6356992);
  float* CV1  = ws + 6422528;
  float* PR1  = ws + 6438912;
  float* CV2  = ws + 6455296;
  float* PR2  = ws + 6471680;                              // end 6,488,064 floats ~= 24.8 MiB
  float* outp = (float*)d_out;

  k_conv1   <<<dim3(64, 2, 2), 256, 0, stream>>>(f1, f2, cw1, cw2, cb1, cb2, CV1);
  k_softmax <<<4, 256, 0, stream>>>(CV1, PR1);
  k_scale_cl<<<dim3(64, 2, 2), 256, 0, stream>>>(f1, f2, PR1, pw1, pw2, pb1, pb2,
                                                 FS1, FS2, CLT1, CLT2);
  k_hat     <<<dim3(128, 2, 4), 256, 0, stream>>>(FS1, FS2, CLT1, CLT2, HAT1, HAT2);
  k_norm    <<<dim3(64, 2, 2), 256, 0, stream>>>(HAT1, HAT2, f1, f2, cw1, cw2, cb1, cb2, CV2);
  k_softmax <<<4, 256, 0, stream>>>(CV2, PR2);
  k_final   <<<dim3(2048, 1, 2), 256, 0, stream>>>(HAT1, HAT2, PR2, outp);
}

// Round 4
// 136.522 us; speedup vs baseline: 2.4082x; 2.4082x over previous
//
#include <hip/hip_runtime.h>
#include <hip/hip_bf16.h>
#include <math.h>

#define N_B 2
#define C_CH 256
#define HW_SZ 4096
#define CL_CH 16

typedef __bf16 bf16x8 __attribute__((ext_vector_type(8)));
typedef float f32x4 __attribute__((ext_vector_type(4)));
typedef float f32x16 __attribute__((ext_vector_type(16)));

__device__ __forceinline__ unsigned short f2bf(float x){
  __hip_bfloat16 b = __float2bfloat16(x);   // RTNE
  return *reinterpret_cast<unsigned short*>(&b);
}
__device__ __forceinline__ unsigned int pack_bf2(float a, float b){
  return (unsigned int)f2bf(a) | ((unsigned int)f2bf(b) << 16);
}
// tanh, NaN-safe: 1 - 2/(1+e^{2x})
__device__ __forceinline__ float tanh_fast(float x){
  float e = __expf(2.0f * x);
  return 1.0f - 2.0f / (1.0f + e);
}
// async global->LDS, 16B per lane; dst must be wave-uniform base (+lane*16 implicit)
__device__ __forceinline__ void gload16(const void* gsrc, void* lds_dst){
  __builtin_amdgcn_global_load_lds(
      (const __attribute__((address_space(1))) unsigned int*)gsrc,
      (__attribute__((address_space(3))) unsigned int*)lds_dst, 16, 0, 0);
}

// ---------- Stage-1 conv (C->1)
__global__ void k_conv1(const float* __restrict__ f1, const float* __restrict__ f2,
                        const float* __restrict__ w1, const float* __restrict__ w2,
                        const float* __restrict__ b1, const float* __restrict__ b2,
                        float* __restrict__ cv){
  const int i = blockIdx.z, n = blockIdx.y, t = threadIdx.x;
  const int ql = t & 63, cg = t >> 6;
  const int q = blockIdx.x * 64 + ql;
  const float* f = (i ? f2 : f1) + n * C_CH * HW_SZ;
  const float* w = i ? w2 : w1;
  __shared__ float ws[C_CH];
  __shared__ float red[4][72];
  ws[t] = w[t];
  __syncthreads();
  float acc = 0.f;
  #pragma unroll 8
  for (int c = cg * 64; c < cg * 64 + 64; ++c)
    acc += f[c * HW_SZ + q] * ws[c];
  red[cg][ql] = acc;
  __syncthreads();
  if (t < 64){
    float s = red[0][t] + red[1][t] + red[2][t] + red[3][t] + (i ? b2[0] : b1[0]);
    cv[(i * 2 + n) * HW_SZ + blockIdx.x * 64 + t] = s;
  }
}

// ---------- softmax over 4096 per row; grid(4) block 256
__global__ void k_softmax(const float* __restrict__ cv, float* __restrict__ pr){
  const int r = blockIdx.x, t = threadIdx.x;
  const float* x = cv + r * HW_SZ;
  float* y = pr + r * HW_SZ;
  __shared__ float red[256];
  float v[16];
  float m = -1e30f;
  #pragma unroll
  for (int j = 0; j < 16; j++){ v[j] = x[j * 256 + t]; m = fmaxf(m, v[j]); }
  red[t] = m; __syncthreads();
  for (int s = 128; s > 0; s >>= 1){ if (t < s) red[t] = fmaxf(red[t], red[t + s]); __syncthreads(); }
  m = red[0]; __syncthreads();
  float sum = 0.f;
  #pragma unroll
  for (int j = 0; j < 16; j++){ v[j] = __expf(v[j] - m); sum += v[j]; }
  red[t] = sum; __syncthreads();
  for (int s = 128; s > 0; s >>= 1){ if (t < s) red[t] += red[t + s]; __syncthreads(); }
  const float inv = 1.0f / red[0];
  #pragma unroll
  for (int j = 0; j < 16; j++) y[j * 256 + t] = v[j] * inv;
}

// ---------- fs_i = bf16(pr_i * f_i) ; clT_i[q][k] = bf16(pw_i @ (pr*f) + pb_i)
__global__ void k_scale_cl(const float* __restrict__ f1, const float* __restrict__ f2,
                           const float* __restrict__ pr,
                           const float* __restrict__ pw1, const float* __restrict__ pw2,
                           const float* __restrict__ pb1, const float* __restrict__ pb2,
                           unsigned short* __restrict__ fs1, unsigned short* __restrict__ fs2,
                           unsigned short* __restrict__ clT1, unsigned short* __restrict__ clT2){
  const int i = blockIdx.z, n = blockIdx.y, t = threadIdx.x;
  const int ql = t & 63, cg = t >> 6;
  const int q = blockIdx.x * 64 + ql;
  const float* f = (i ? f2 : f1) + n * C_CH * HW_SZ;
  unsigned short* fs = (i ? fs2 : fs1) + n * C_CH * HW_SZ;
  unsigned short* clT = (i ? clT2 : clT1) + n * CL_CH * HW_SZ;
  const float* pw = i ? pw2 : pw1;
  const float* pb = i ? pb2 : pb1;
  __shared__ float wls[CL_CH * C_CH];
  __shared__ float red[4][CL_CH][66];
  #pragma unroll
  for (int j = 0; j < 16; j++) wls[j * 256 + t] = pw[j * 256 + t];
  __syncthreads();
  const float p = pr[(i * 2 + n) * HW_SZ + q];
  float acc[16];
  #pragma unroll
  for (int k = 0; k < 16; k++) acc[k] = 0.f;
  for (int c = cg * 64; c < cg * 64 + 64; ++c){
    float vv = f[c * HW_SZ + q] * p;
    fs[c * HW_SZ + q] = f2bf(vv);
    #pragma unroll
    for (int k = 0; k < 16; k++) acc[k] += wls[k * 256 + c] * vv;
  }
  #pragma unroll
  for (int k = 0; k < 16; k++) red[cg][k][ql] = acc[k];
  __syncthreads();
  #pragma unroll
  for (int j = 0; j < 4; j++){
    int e = j * 256 + t; int k = e >> 6, qq = e & 63;
    float s = red[0][k][qq] + red[1][k][qq] + red[2][k][qq] + red[3][k][qq] + pb[k];
    clT[(blockIdx.x * 64 + qq) * CL_CH + k] = f2bf(s);
  }
}

// ---------- fused hat GEMM via MFMA.
// out[c,q] = sum_p fs[c,p] * tanh(sum_k v[k,p]*u[k,q])
// grid 256 flat (XCD-swizzled to (x qtile, n, i)), block 512 (8 waves).
// Tile: full C=256 x 64 q; K-loop p in 64-chunks; one __syncthreads per chunk.
__global__ __launch_bounds__(512, 2) void k_hat(
    const unsigned short* __restrict__ fs1, const unsigned short* __restrict__ fs2,
    const unsigned short* __restrict__ clT1, const unsigned short* __restrict__ clT2,
    float* __restrict__ hat1, float* __restrict__ hat2){
  const int t = threadIdx.x;
  // XCD swizzle: xcd = bid&7 (round-robin); give each (n,i) a dedicated XCD pair
  const int bid = blockIdx.x;
  const int xcd = bid & 7, slot = bid >> 3;
  const int z = xcd >> 1;                    // 0..3 -> (n,i)
  const int n = z & 1, i = z >> 1;
  const int x = slot * 2 + (xcd & 1);        // 0..63 q-tile
  const int q0 = x * 64;

  const unsigned short* fs = (i ? fs2 : fs1) + n * C_CH * HW_SZ;
  const unsigned short* uT = (i ? clT1 : clT2) + n * CL_CH * HW_SZ;  // q-side [HW][16]
  const unsigned short* vT = (i ? clT2 : clT1) + n * CL_CH * HW_SZ;  // p-side [HW][16]
  float* out = (i ? hat2 : hat1) + n * C_CH * HW_SZ;

  __shared__ __align__(16) unsigned short fsA[2][C_CH * 64];  // [c][p-chunk swz] 32KB each
  __shared__ __align__(16) unsigned short vB[2][64 * 16];     // [p][k] 2KB each
  __shared__ __align__(16) unsigned short aT[2][64 * 64];     // [q][p-chunk swz] 8KB each

  const int wv = t >> 6, l = t & 63;
  const int g4 = l >> 4, lr16 = l & 15;      // d-gen (16x16)
  const int g2 = l >> 5, lr32 = l & 31;      // main (32x32)
  const int c0w = (wv >> 1) * 64, q0w = (wv & 1) * 32;

  // ---- one-time u fragment (B-op of d-gen): wave handles q-block qd = wv&3
  bf16x8 ub;
  #pragma unroll
  for (int j = 0; j < 8; j++) ub[j] = (__bf16)0.0f;
  if (g4 < 2)
    ub = *reinterpret_cast<const bf16x8*>(&uT[(q0 + (wv & 3) * 16 + lr16) * CL_CH + g4 * 8]);

  f32x16 acc[2];
  #pragma unroll
  for (int cf = 0; cf < 2; ++cf)
    #pragma unroll
    for (int r = 0; r < 16; ++r) acc[cf][r] = 0.f;
  const f32x4 zz = {0.f, 0.f, 0.f, 0.f};

  // ---- staging helpers (all per-chunk issue counts wave-uniform)
  auto stage_fs = [&](int buf, int p0){
    #pragma unroll
    for (int it = 0; it < 4; ++it){
      int d = it * 512 + t;                  // 16B-chunk index in [0,2048)
      int c = d >> 3, col = d & 7;
      gload16(&fs[c * HW_SZ + p0 + ((col ^ (c & 7)) * 8)],
              (void*)&fsA[buf][(it * 512 + wv * 64) * 8]);
    }
  };
  auto stage_v = [&](int buf, int p0){
    if (l < 16){
      int chunk = wv * 16 + l;               // 16B chunk of the 2KB tile
      int p = chunk >> 1, half = chunk & 1;
      gload16(&vT[(p0 + p) * CL_CH + half * 8], (void*)&vB[buf][wv * 128]);
    }
  };

  auto dgen = [&](int kk){                   // produce aT[kk&1] from vB[kk&1]
    const unsigned short* vb = vB[kk & 1];
    unsigned short* at = aT[kk & 1];
    const int qd = wv & 3, pb = (wv >> 2) * 2;
    #pragma unroll
    for (int s = 0; s < 2; ++s){
      int pf = pb + s;
      bf16x8 av;
      #pragma unroll
      for (int j = 0; j < 8; j++) av[j] = (__bf16)0.0f;
      if (g4 < 2)
        av = *reinterpret_cast<const bf16x8*>(&vb[(pf * 16 + lr16) * 16 + g4 * 8]);
      f32x4 dv = __builtin_amdgcn_mfma_f32_16x16x32_bf16(av, ub, zz, 0, 0, 0);
      // lane holds D[p = pf*16 + 4*g4 + r][q = qd*16 + lr16]
      int q = qd * 16 + lr16;
      unsigned int lo = pack_bf2(tanh_fast(dv[0]), tanh_fast(dv[1]));
      unsigned int hi = pack_bf2(tanh_fast(dv[2]), tanh_fast(dv[3]));
      int chunk = pf * 2 + (g4 >> 1);
      uint2 pk = {lo, hi};
      *reinterpret_cast<uint2*>(&at[q * 64 + ((chunk ^ (q & 7)) * 8) + (g4 & 1) * 4]) = pk;
    }
  };

  // ---- prologue: fs(0), v(0), v(1); then a(0)
  stage_fs(0, 0);
  stage_v(0, 0);
  stage_v(1, 64);
  __syncthreads();
  dgen(0);
  __syncthreads();

  // ---- main loop: 64 chunks of p
  for (int k = 0; k < 64; ++k){
    stage_fs((k + 1) & 1, ((k + 1) & 63) * 64);
    stage_v(k & 1, ((k + 2) & 63) * 64);
    if (k + 1 < 64) dgen(k + 1);
    // main MFMA: D[c][q] += fs[c][p] * a[q][p], K=64 as 4 steps of 16
    const unsigned short* fa = fsA[k & 1];
    const unsigned short* at = aT[k & 1];
    #pragma unroll
    for (int ks = 0; ks < 4; ++ks){
      int qrow = q0w + lr32;
      bf16x8 bq = *reinterpret_cast<const bf16x8*>(
          &at[qrow * 64 + (((ks * 2 + g2) ^ (qrow & 7)) * 8)]);
      #pragma unroll
      for (int cf = 0; cf < 2; ++cf){
        int crow = c0w + cf * 32 + lr32;
        bf16x8 af = *reinterpret_cast<const bf16x8*>(
            &fa[crow * 64 + (((ks * 2 + g2) ^ (crow & 7)) * 8)]);
        acc[cf] = __builtin_amdgcn_mfma_f32_32x32x16_bf16(af, bq, acc[cf], 0, 0, 0);
      }
    }
    __syncthreads();   // drains this chunk's gload_lds + all LDS ops
  }

  // ---- store: 32x32 C-layout: col=lane&31, row=(reg&3)+8*(reg>>2)+4*(lane>>5)
  const int qcol = q0 + q0w + lr32;
  #pragma unroll
  for (int cf = 0; cf < 2; ++cf){
    #pragma unroll
    for (int r = 0; r < 16; ++r){
      int c = c0w + cf * 32 + (r & 3) + 8 * (r >> 2) + 4 * g2;
      out[c * HW_SZ + qcol] = acc[cf][r];
    }
  }
}

// ---------- l2norm(channels) + residual + relu (IN-PLACE into hat) + stage-2 conv
__global__ void k_norm(float* __restrict__ hat1, float* __restrict__ hat2,
                       const float* __restrict__ f1, const float* __restrict__ f2,
                       const float* __restrict__ cw1, const float* __restrict__ cw2,
                       const float* __restrict__ cb1, const float* __restrict__ cb2,
                       float* __restrict__ cv2){
  const int i = blockIdx.z, n = blockIdx.y, t = threadIdx.x;
  const int ql = t & 63, cg = t >> 6;
  const int q = blockIdx.x * 64 + ql;
  float* hat = (i ? hat2 : hat1) + n * C_CH * HW_SZ;
  const float* f = (i ? f2 : f1) + n * C_CH * HW_SZ;
  __shared__ float ws[C_CH];
  __shared__ float red[4][72];
  __shared__ float invs[64];
  ws[t] = (i ? cw2 : cw1)[t];
  __syncthreads();
  float s = 0.f;
  #pragma unroll 8
  for (int c = cg * 64; c < cg * 64 + 64; ++c){ float h = hat[c * HW_SZ + q]; s += h * h; }
  red[cg][ql] = s; __syncthreads();
  if (t < 64){
    float ss = red[0][t] + red[1][t] + red[2][t] + red[3][t];
    invs[t] = 1.0f / fmaxf(sqrtf(ss), 1e-12f);
  }
  __syncthreads();
  const float inv = invs[ql];
  float ca = 0.f;
  #pragma unroll 8
  for (int c = cg * 64; c < cg * 64 + 64; ++c){
    float vv = fmaxf(hat[c * HW_SZ + q] * inv + f[c * HW_SZ + q], 0.0f);
    hat[c * HW_SZ + q] = vv;  // in-place: only this thread touches [c][q]
    ca += ws[c] * vv;
  }
  red[cg][ql] = ca; __syncthreads();
  if (t < 64){
    float ss = red[0][t] + red[1][t] + red[2][t] + red[3][t] + (i ? cb2[0] : cb1[0]);
    cv2[(i * 2 + n) * HW_SZ + blockIdx.x * 64 + t] = ss;
  }
}

// ---------- final: out_i = pr2_i * fp_i
__global__ void k_final(const float* __restrict__ fp1, const float* __restrict__ fp2,
                        const float* __restrict__ pr2, float* __restrict__ outp){
  const int i = blockIdx.z;
  const int idx4 = (blockIdx.x * 256 + threadIdx.x) * 4;
  const int n = idx4 >> 20;
  const int q = idx4 & (HW_SZ - 1);
  const float* fp = i ? fp2 : fp1;
  float4 vv = *reinterpret_cast<const float4*>(&fp[idx4]);
  float4 pp = *reinterpret_cast<const float4*>(&pr2[(i * 2 + n) * HW_SZ + q]);
  float4 o; o.x = vv.x * pp.x; o.y = vv.y * pp.y; o.z = vv.z * pp.z; o.w = vv.w * pp.w;
  *reinterpret_cast<float4*>(&outp[i * (C_CH * HW_SZ * N_B) + idx4]) = o;
}

extern "C" void kernel_launch(void* const* d_in, const int* in_sizes, int n_in,
                              void* d_out, int out_size, void* d_ws, size_t ws_size,
                              hipStream_t stream){
  const float* f1  = (const float*)d_in[0];
  const float* f2  = (const float*)d_in[1];
  const float* pw1 = (const float*)d_in[2];
  const float* pb1 = (const float*)d_in[3];
  const float* pw2 = (const float*)d_in[4];
  const float* pb2 = (const float*)d_in[5];
  const float* cw1 = (const float*)d_in[6];
  const float* cb1 = (const float*)d_in[7];
  const float* cw2 = (const float*)d_in[8];
  const float* cb2 = (const float*)d_in[9];
  float* ws = (float*)d_ws;
  // layout (float offsets): HAT doubles as FP (k_norm in-place, k_final reads it)
  float* HAT1 = ws;                                        // 2,097,152 floats
  float* HAT2 = ws + 2097152;
  unsigned short* FS1 = (unsigned short*)(ws + 4194304);   // bf16 [C][HW] per n
  unsigned short* FS2 = (unsigned short*)(ws + 5242880);
  unsigned short* CLT1 = (unsigned short*)(ws + 6291456);  // bf16 [HW][16] per n
  unsigned short* CLT2 = (unsigned short*)(ws + 6356992);
  float* CV1  = ws + 6422528;
  float* PR1  = ws + 6438912;
  float* CV2  = ws + 6455296;
  float* PR2  = ws + 6471680;                              // end 6,488,064 floats ~= 24.8 MiB
  float* outp = (float*)d_out;

  k_conv1   <<<dim3(64, 2, 2), 256, 0, stream>>>(f1, f2, cw1, cw2, cb1, cb2, CV1);
  k_softmax <<<4, 256, 0, stream>>>(CV1, PR1);
  k_scale_cl<<<dim3(64, 2, 2), 256, 0, stream>>>(f1, f2, PR1, pw1, pw2, pb1, pb2,
                                                 FS1, FS2, CLT1, CLT2);
  k_hat     <<<256, 512, 0, stream>>>(FS1, FS2, CLT1, CLT2, HAT1, HAT2);
  k_norm    <<<dim3(64, 2, 2), 256, 0, stream>>>(HAT1, HAT2, f1, f2, cw1, cw2, cb1, cb2, CV2);
  k_softmax <<<4, 256, 0, stream>>>(CV2, PR2);
  k_final   <<<dim3(2048, 1, 2), 256, 0, stream>>>(HAT1, HAT2, PR2, outp);
}

// Round 5
// 134.880 us; speedup vs baseline: 2.4375x; 1.0122x over previous
//
#include <hip/hip_runtime.h>
#include <hip/hip_bf16.h>
#include <math.h>

#define N_B 2
#define C_CH 256
#define HW_SZ 4096
#define CL_CH 16

typedef __bf16 bf16x8 __attribute__((ext_vector_type(8)));
typedef float f32x4 __attribute__((ext_vector_type(4)));
typedef float f32x16 __attribute__((ext_vector_type(16)));

__device__ __forceinline__ unsigned short f2bf(float x){
  __hip_bfloat16 b = __float2bfloat16(x);   // RTNE
  return *reinterpret_cast<unsigned short*>(&b);
}
__device__ __forceinline__ unsigned int pack_bf2(float a, float b){
  return (unsigned int)f2bf(a) | ((unsigned int)f2bf(b) << 16);
}
// tanh, NaN-safe: 1 - 2/(1+e^{2x})
__device__ __forceinline__ float tanh_fast(float x){
  float e = __expf(2.0f * x);
  return 1.0f - 2.0f / (1.0f + e);
}
// async global->LDS, 16B per lane; dst must be wave-uniform base (+lane*16 implicit)
__device__ __forceinline__ void gload16(const void* gsrc, void* lds_dst){
  __builtin_amdgcn_global_load_lds(
      (const __attribute__((address_space(1))) unsigned int*)gsrc,
      (__attribute__((address_space(3))) unsigned int*)lds_dst, 16, 0, 0);
}

// ---------- Stage-1 conv (C->1)
__global__ void k_conv1(const float* __restrict__ f1, const float* __restrict__ f2,
                        const float* __restrict__ w1, const float* __restrict__ w2,
                        const float* __restrict__ b1, const float* __restrict__ b2,
                        float* __restrict__ cv){
  const int i = blockIdx.z, n = blockIdx.y, t = threadIdx.x;
  const int ql = t & 63, cg = t >> 6;
  const int q = blockIdx.x * 64 + ql;
  const float* f = (i ? f2 : f1) + n * C_CH * HW_SZ;
  const float* w = i ? w2 : w1;
  __shared__ float ws[C_CH];
  __shared__ float red[4][72];
  ws[t] = w[t];
  __syncthreads();
  float acc = 0.f;
  #pragma unroll 8
  for (int c = cg * 64; c < cg * 64 + 64; ++c)
    acc += f[c * HW_SZ + q] * ws[c];
  red[cg][ql] = acc;
  __syncthreads();
  if (t < 64){
    float s = red[0][t] + red[1][t] + red[2][t] + red[3][t] + (i ? b2[0] : b1[0]);
    cv[(i * 2 + n) * HW_SZ + blockIdx.x * 64 + t] = s;
  }
}

// ---------- softmax over 4096 per row; grid(4) block 256
__global__ void k_softmax(const float* __restrict__ cv, float* __restrict__ pr){
  const int r = blockIdx.x, t = threadIdx.x;
  const float* x = cv + r * HW_SZ;
  float* y = pr + r * HW_SZ;
  __shared__ float red[256];
  float v[16];
  float m = -1e30f;
  #pragma unroll
  for (int j = 0; j < 16; j++){ v[j] = x[j * 256 + t]; m = fmaxf(m, v[j]); }
  red[t] = m; __syncthreads();
  for (int s = 128; s > 0; s >>= 1){ if (t < s) red[t] = fmaxf(red[t], red[t + s]); __syncthreads(); }
  m = red[0]; __syncthreads();
  float sum = 0.f;
  #pragma unroll
  for (int j = 0; j < 16; j++){ v[j] = __expf(v[j] - m); sum += v[j]; }
  red[t] = sum; __syncthreads();
  for (int s = 128; s > 0; s >>= 1){ if (t < s) red[t] += red[t + s]; __syncthreads(); }
  const float inv = 1.0f / red[0];
  #pragma unroll
  for (int j = 0; j < 16; j++) y[j * 256 + t] = v[j] * inv;
}

// ---------- fs_i = bf16(pr_i * f_i) ; clT_i[q][k] = bf16(pw_i @ (pr*f) + pb_i)
__global__ void k_scale_cl(const float* __restrict__ f1, const float* __restrict__ f2,
                           const float* __restrict__ pr,
                           const float* __restrict__ pw1, const float* __restrict__ pw2,
                           const float* __restrict__ pb1, const float* __restrict__ pb2,
                           unsigned short* __restrict__ fs1, unsigned short* __restrict__ fs2,
                           unsigned short* __restrict__ clT1, unsigned short* __restrict__ clT2){
  const int i = blockIdx.z, n = blockIdx.y, t = threadIdx.x;
  const int ql = t & 63, cg = t >> 6;
  const int q = blockIdx.x * 64 + ql;
  const float* f = (i ? f2 : f1) + n * C_CH * HW_SZ;
  unsigned short* fs = (i ? fs2 : fs1) + n * C_CH * HW_SZ;
  unsigned short* clT = (i ? clT2 : clT1) + n * CL_CH * HW_SZ;
  const float* pw = i ? pw2 : pw1;
  const float* pb = i ? pb2 : pb1;
  __shared__ float wls[CL_CH * C_CH];
  __shared__ float red[4][CL_CH][66];
  #pragma unroll
  for (int j = 0; j < 16; j++) wls[j * 256 + t] = pw[j * 256 + t];
  __syncthreads();
  const float p = pr[(i * 2 + n) * HW_SZ + q];
  float acc[16];
  #pragma unroll
  for (int k = 0; k < 16; k++) acc[k] = 0.f;
  for (int c = cg * 64; c < cg * 64 + 64; ++c){
    float vv = f[c * HW_SZ + q] * p;
    fs[c * HW_SZ + q] = f2bf(vv);
    #pragma unroll
    for (int k = 0; k < 16; k++) acc[k] += wls[k * 256 + c] * vv;
  }
  #pragma unroll
  for (int k = 0; k < 16; k++) red[cg][k][ql] = acc[k];
  __syncthreads();
  #pragma unroll
  for (int j = 0; j < 4; j++){
    int e = j * 256 + t; int k = e >> 6, qq = e & 63;
    float s = red[0][k][qq] + red[1][k][qq] + red[2][k][qq] + red[3][k][qq] + pb[k];
    clT[(blockIdx.x * 64 + qq) * CL_CH + k] = f2bf(s);
  }
}

// ---------- fused hat GEMM via MFMA.
// out[c,q] = sum_p fs[c,p] * tanh(sum_k v[k,p]*u[k,q])
// grid 512 flat (XCD-swizzled), block 512 (8 waves). Tile: C=256 x 32 q.
// 2 blocks/CU (LDS 76KB) -> barrier stalls of one block hide under the other.
__global__ __launch_bounds__(512, 4) void k_hat(
    const unsigned short* __restrict__ fs1, const unsigned short* __restrict__ fs2,
    const unsigned short* __restrict__ clT1, const unsigned short* __restrict__ clT2,
    float* __restrict__ hat1, float* __restrict__ hat2){
  const int t = threadIdx.x;
  // XCD swizzle: 2 XCDs per (n,i); 2MB fs panel fits each XCD's 4MB L2
  const int bid = blockIdx.x;
  const int xcd = bid & 7, slot = bid >> 3;    // slot 0..63
  const int z = xcd >> 1;                      // 0..3 -> (n,i)
  const int n = z & 1, i = z >> 1;
  const int x = slot * 2 + (xcd & 1);          // 0..127 q-tile
  const int q0 = x * 32;

  const unsigned short* fs = (i ? fs2 : fs1) + n * C_CH * HW_SZ;
  const unsigned short* uT = (i ? clT1 : clT2) + n * CL_CH * HW_SZ;  // q-side [HW][16]
  const unsigned short* vT = (i ? clT2 : clT1) + n * CL_CH * HW_SZ;  // p-side [HW][16]
  float* out = (i ? hat2 : hat1) + n * C_CH * HW_SZ;

  __shared__ __align__(16) unsigned short fsA[2][C_CH * 64];  // [c][p-chunk swz] 32KB each
  __shared__ __align__(16) unsigned short vB[2][64 * 16];     // [p][k] 2KB each
  __shared__ __align__(16) unsigned short aT[2][32 * 64];     // [q][p-chunk swz] 4KB each

  const int wv = t >> 6, l = t & 63;
  const int g4 = l >> 4, lr16 = l & 15;      // d-gen (16x16)
  const int g2 = l >> 5, lr32 = l & 31;      // main (32x32)

  // ---- one-time u fragment (B-op of d-gen): wave wv handles (pf = wv&3, qf = wv>>2)
  const int pfw = wv & 3, qfw = wv >> 2;
  bf16x8 ub;
  #pragma unroll
  for (int j = 0; j < 8; j++) ub[j] = (__bf16)0.0f;
  if (g4 < 2)
    ub = *reinterpret_cast<const bf16x8*>(&uT[(q0 + qfw * 16 + lr16) * CL_CH + g4 * 8]);

  f32x16 acc;
  #pragma unroll
  for (int r = 0; r < 16; ++r) acc[r] = 0.f;
  const f32x4 zz = {0.f, 0.f, 0.f, 0.f};

  // ---- staging helpers
  auto stage_fs = [&](int buf, int p0){
    #pragma unroll
    for (int it = 0; it < 4; ++it){
      int d = it * 512 + t;                  // 16B-chunk index in [0,2048)
      int c = d >> 3, col = d & 7;
      gload16(&fs[c * HW_SZ + p0 + ((col ^ (c & 7)) * 8)],
              (void*)&fsA[buf][(it * 512 + wv * 64) * 8]);
    }
  };
  auto stage_v = [&](int buf, int p0){
    if (l < 16){
      int chunk = wv * 16 + l;               // 16B chunk of the 2KB tile
      int p = chunk >> 1, half = chunk & 1;
      gload16(&vT[(p0 + p) * CL_CH + half * 8], (void*)&vB[buf][wv * 128]);
    }
  };

  auto dgen = [&](int kk){                   // produce aT[kk&1] from vB[kk&1]
    const unsigned short* vb = vB[kk & 1];
    unsigned short* at = aT[kk & 1];
    bf16x8 av;
    #pragma unroll
    for (int j = 0; j < 8; j++) av[j] = (__bf16)0.0f;
    if (g4 < 2)
      av = *reinterpret_cast<const bf16x8*>(&vb[(pfw * 16 + lr16) * 16 + g4 * 8]);
    f32x4 dv = __builtin_amdgcn_mfma_f32_16x16x32_bf16(av, ub, zz, 0, 0, 0);
    // lane holds D[p = pfw*16 + 4*g4 + r][q = qfw*16 + lr16]
    int q = qfw * 16 + lr16;
    unsigned int lo = pack_bf2(tanh_fast(dv[0]), tanh_fast(dv[1]));
    unsigned int hi = pack_bf2(tanh_fast(dv[2]), tanh_fast(dv[3]));
    int chunk = pfw * 2 + (g4 >> 1);
    uint2 pk = {lo, hi};
    *reinterpret_cast<uint2*>(&at[q * 64 + ((chunk ^ (q & 7)) * 8) + (g4 & 1) * 4]) = pk;
  };

  // ---- prologue: fs(0), v(0), v(1); then a(0)
  stage_fs(0, 0);
  stage_v(0, 0);
  stage_v(1, 64);
  __syncthreads();
  dgen(0);
  __syncthreads();

  // ---- main loop: 64 chunks of p
  for (int k = 0; k < 64; ++k){
    stage_fs((k + 1) & 1, ((k + 1) & 63) * 64);
    stage_v(k & 1, ((k + 2) & 63) * 64);
    if (k + 1 < 64) dgen(k + 1);
    // main MFMA: D[c][q] += fs[c][p] * a[q][p], K=64 as 4 steps of 16
    const unsigned short* fa = fsA[k & 1];
    const unsigned short* at = aT[k & 1];
    #pragma unroll
    for (int ks = 0; ks < 4; ++ks){
      int qrow = lr32;
      bf16x8 bq = *reinterpret_cast<const bf16x8*>(
          &at[qrow * 64 + (((ks * 2 + g2) ^ (qrow & 7)) * 8)]);
      int crow = wv * 32 + lr32;
      bf16x8 af = *reinterpret_cast<const bf16x8*>(
          &fa[crow * 64 + (((ks * 2 + g2) ^ (crow & 7)) * 8)]);
      acc = __builtin_amdgcn_mfma_f32_32x32x16_bf16(af, bq, acc, 0, 0, 0);
    }
    __syncthreads();   // drains this chunk's gload_lds + all LDS ops
  }

  // ---- store: 32x32 C-layout: col(=q)=lane&31, row(=c)=(reg&3)+8*(reg>>2)+4*(lane>>5)
  const int qcol = q0 + lr32;
  #pragma unroll
  for (int r = 0; r < 16; ++r){
    int c = wv * 32 + (r & 3) + 8 * (r >> 2) + 4 * g2;
    out[c * HW_SZ + qcol] = acc[r];
  }
}

// ---------- l2norm(channels) + residual + relu (IN-PLACE into hat) + stage-2 conv
__global__ void k_norm(float* __restrict__ hat1, float* __restrict__ hat2,
                       const float* __restrict__ f1, const float* __restrict__ f2,
                       const float* __restrict__ cw1, const float* __restrict__ cw2,
                       const float* __restrict__ cb1, const float* __restrict__ cb2,
                       float* __restrict__ cv2){
  const int i = blockIdx.z, n = blockIdx.y, t = threadIdx.x;
  const int ql = t & 63, cg = t >> 6;
  const int q = blockIdx.x * 64 + ql;
  float* hat = (i ? hat2 : hat1) + n * C_CH * HW_SZ;
  const float* f = (i ? f2 : f1) + n * C_CH * HW_SZ;
  __shared__ float ws[C_CH];
  __shared__ float red[4][72];
  __shared__ float invs[64];
  ws[t] = (i ? cw2 : cw1)[t];
  __syncthreads();
  float s = 0.f;
  #pragma unroll 8
  for (int c = cg * 64; c < cg * 64 + 64; ++c){ float h = hat[c * HW_SZ + q]; s += h * h; }
  red[cg][ql] = s; __syncthreads();
  if (t < 64){
    float ss = red[0][t] + red[1][t] + red[2][t] + red[3][t];
    invs[t] = 1.0f / fmaxf(sqrtf(ss), 1e-12f);
  }
  __syncthreads();
  const float inv = invs[ql];
  float ca = 0.f;
  #pragma unroll 8
  for (int c = cg * 64; c < cg * 64 + 64; ++c){
    float vv = fmaxf(hat[c * HW_SZ + q] * inv + f[c * HW_SZ + q], 0.0f);
    hat[c * HW_SZ + q] = vv;  // in-place: only this thread touches [c][q]
    ca += ws[c] * vv;
  }
  red[cg][ql] = ca; __syncthreads();
  if (t < 64){
    float ss = red[0][t] + red[1][t] + red[2][t] + red[3][t] + (i ? cb2[0] : cb1[0]);
    cv2[(i * 2 + n) * HW_SZ + blockIdx.x * 64 + t] = ss;
  }
}

// ---------- final: out_i = pr2_i * fp_i
__global__ void k_final(const float* __restrict__ fp1, const float* __restrict__ fp2,
                        const float* __restrict__ pr2, float* __restrict__ outp){
  const int i = blockIdx.z;
  const int idx4 = (blockIdx.x * 256 + threadIdx.x) * 4;
  const int n = idx4 >> 20;
  const int q = idx4 & (HW_SZ - 1);
  const float* fp = i ? fp2 : fp1;
  float4 vv = *reinterpret_cast<const float4*>(&fp[idx4]);
  float4 pp = *reinterpret_cast<const float4*>(&pr2[(i * 2 + n) * HW_SZ + q]);
  float4 o; o.x = vv.x * pp.x; o.y = vv.y * pp.y; o.z = vv.z * pp.z; o.w = vv.w * pp.w;
  *reinterpret_cast<float4*>(&outp[i * (C_CH * HW_SZ * N_B) + idx4]) = o;
}

extern "C" void kernel_launch(void* const* d_in, const int* in_sizes, int n_in,
                              void* d_out, int out_size, void* d_ws, size_t ws_size,
                              hipStream_t stream){
  const float* f1  = (const float*)d_in[0];
  const float* f2  = (const float*)d_in[1];
  const float* pw1 = (const float*)d_in[2];
  const float* pb1 = (const float*)d_in[3];
  const float* pw2 = (const float*)d_in[4];
  const float* pb2 = (const float*)d_in[5];
  const float* cw1 = (const float*)d_in[6];
  const float* cb1 = (const float*)d_in[7];
  const float* cw2 = (const float*)d_in[8];
  const float* cb2 = (const float*)d_in[9];
  float* ws = (float*)d_ws;
  // layout (float offsets): HAT doubles as FP (k_norm in-place, k_final reads it)
  float* HAT1 = ws;                                        // 2,097,152 floats
  float* HAT2 = ws + 2097152;
  unsigned short* FS1 = (unsigned short*)(ws + 4194304);   // bf16 [C][HW] per n
  unsigned short* FS2 = (unsigned short*)(ws + 5242880);
  unsigned short* CLT1 = (unsigned short*)(ws + 6291456);  // bf16 [HW][16] per n
  unsigned short* CLT2 = (unsigned short*)(ws + 6356992);
  float* CV1  = ws + 6422528;
  float* PR1  = ws + 6438912;
  float* CV2  = ws + 6455296;
  float* PR2  = ws + 6471680;                              // end 6,488,064 floats ~= 24.8 MiB
  float* outp = (float*)d_out;

  k_conv1   <<<dim3(64, 2, 2), 256, 0, stream>>>(f1, f2, cw1, cw2, cb1, cb2, CV1);
  k_softmax <<<4, 256, 0, stream>>>(CV1, PR1);
  k_scale_cl<<<dim3(64, 2, 2), 256, 0, stream>>>(f1, f2, PR1, pw1, pw2, pb1, pb2,
                                                 FS1, FS2, CLT1, CLT2);
  k_hat     <<<512, 512, 0, stream>>>(FS1, FS2, CLT1, CLT2, HAT1, HAT2);
  k_norm    <<<dim3(64, 2, 2), 256, 0, stream>>>(HAT1, HAT2, f1, f2, cw1, cw2, cb1, cb2, CV2);
  k_softmax <<<4, 256, 0, stream>>>(CV2, PR2);
  k_final   <<<dim3(2048, 1, 2), 256, 0, stream>>>(HAT1, HAT2, PR2, outp);
}

// Round 6
// 125.717 us; speedup vs baseline: 2.6152x; 1.0729x over previous
//
#include <hip/hip_runtime.h>
#include <hip/hip_bf16.h>
#include <math.h>

#define N_B 2
#define C_CH 256
#define HW_SZ 4096
#define CL_CH 16

typedef __bf16 bf16x8 __attribute__((ext_vector_type(8)));
typedef float f32x4 __attribute__((ext_vector_type(4)));
typedef float f32x16 __attribute__((ext_vector_type(16)));

__device__ __forceinline__ unsigned short f2bf(float x){
  __hip_bfloat16 b = __float2bfloat16(x);   // RTNE
  return *reinterpret_cast<unsigned short*>(&b);
}
__device__ __forceinline__ unsigned int pack_bf2(float a, float b){
  return (unsigned int)f2bf(a) | ((unsigned int)f2bf(b) << 16);
}
// tanh, NaN-safe: 1 - 2/(1+e^{2x})
__device__ __forceinline__ float tanh_fast(float x){
  float e = __expf(2.0f * x);
  return 1.0f - 2.0f / (1.0f + e);
}
// async global->LDS, 16B per lane; dst must be wave-uniform base (+lane*16 implicit)
__device__ __forceinline__ void gload16(const void* gsrc, void* lds_dst){
  __builtin_amdgcn_global_load_lds(
      (const __attribute__((address_space(1))) unsigned int*)gsrc,
      (__attribute__((address_space(3))) unsigned int*)lds_dst, 16, 0, 0);
}

// ---------- Stage-1 conv (C->1)
__global__ void k_conv1(const float* __restrict__ f1, const float* __restrict__ f2,
                        const float* __restrict__ w1, const float* __restrict__ w2,
                        const float* __restrict__ b1, const float* __restrict__ b2,
                        float* __restrict__ cv){
  const int i = blockIdx.z, n = blockIdx.y, t = threadIdx.x;
  const int ql = t & 63, cg = t >> 6;
  const int q = blockIdx.x * 64 + ql;
  const float* f = (i ? f2 : f1) + n * C_CH * HW_SZ;
  const float* w = i ? w2 : w1;
  __shared__ float ws[C_CH];
  __shared__ float red[4][72];
  ws[t] = w[t];
  __syncthreads();
  float acc = 0.f;
  #pragma unroll 8
  for (int c = cg * 64; c < cg * 64 + 64; ++c)
    acc += f[c * HW_SZ + q] * ws[c];
  red[cg][ql] = acc;
  __syncthreads();
  if (t < 64){
    float s = red[0][t] + red[1][t] + red[2][t] + red[3][t] + (i ? b2[0] : b1[0]);
    cv[(i * 2 + n) * HW_SZ + blockIdx.x * 64 + t] = s;
  }
}

// ---------- softmax over 4096 per row; grid(4) block 256
__global__ void k_softmax(const float* __restrict__ cv, float* __restrict__ pr){
  const int r = blockIdx.x, t = threadIdx.x;
  const float* x = cv + r * HW_SZ;
  float* y = pr + r * HW_SZ;
  __shared__ float red[256];
  float v[16];
  float m = -1e30f;
  #pragma unroll
  for (int j = 0; j < 16; j++){ v[j] = x[j * 256 + t]; m = fmaxf(m, v[j]); }
  red[t] = m; __syncthreads();
  for (int s = 128; s > 0; s >>= 1){ if (t < s) red[t] = fmaxf(red[t], red[t + s]); __syncthreads(); }
  m = red[0]; __syncthreads();
  float sum = 0.f;
  #pragma unroll
  for (int j = 0; j < 16; j++){ v[j] = __expf(v[j] - m); sum += v[j]; }
  red[t] = sum; __syncthreads();
  for (int s = 128; s > 0; s >>= 1){ if (t < s) red[t] += red[t + s]; __syncthreads(); }
  const float inv = 1.0f / red[0];
  #pragma unroll
  for (int j = 0; j < 16; j++) y[j * 256 + t] = v[j] * inv;
}

// ---------- fs_i = bf16(pr_i * f_i) ; clT_i[q][0..15] = bf16(pw_i @ (pr*f) + pb_i),
// clT rows are 32 wide with k in [16,32) zeroed (branch-free MFMA fragments in k_hat)
__global__ void k_scale_cl(const float* __restrict__ f1, const float* __restrict__ f2,
                           const float* __restrict__ pr,
                           const float* __restrict__ pw1, const float* __restrict__ pw2,
                           const float* __restrict__ pb1, const float* __restrict__ pb2,
                           unsigned short* __restrict__ fs1, unsigned short* __restrict__ fs2,
                           unsigned short* __restrict__ clT1, unsigned short* __restrict__ clT2){
  const int i = blockIdx.z, n = blockIdx.y, t = threadIdx.x;
  const int ql = t & 63, cg = t >> 6;
  const int q = blockIdx.x * 64 + ql;
  const float* f = (i ? f2 : f1) + n * C_CH * HW_SZ;
  unsigned short* fs = (i ? fs2 : fs1) + n * C_CH * HW_SZ;
  unsigned short* clT = (i ? clT2 : clT1) + n * 32 * HW_SZ;
  const float* pw = i ? pw2 : pw1;
  const float* pb = i ? pb2 : pb1;
  __shared__ float wls[CL_CH * C_CH];
  __shared__ float red[4][CL_CH][66];
  #pragma unroll
  for (int j = 0; j < 16; j++) wls[j * 256 + t] = pw[j * 256 + t];
  __syncthreads();
  const float p = pr[(i * 2 + n) * HW_SZ + q];
  float acc[16];
  #pragma unroll
  for (int k = 0; k < 16; k++) acc[k] = 0.f;
  for (int c = cg * 64; c < cg * 64 + 64; ++c){
    float vv = f[c * HW_SZ + q] * p;
    fs[c * HW_SZ + q] = f2bf(vv);
    #pragma unroll
    for (int k = 0; k < 16; k++) acc[k] += wls[k * 256 + c] * vv;
  }
  #pragma unroll
  for (int k = 0; k < 16; k++) red[cg][k][ql] = acc[k];
  __syncthreads();
  #pragma unroll
  for (int j = 0; j < 4; j++){
    int e = j * 256 + t; int k = e >> 6, qq = e & 63;
    float s = red[0][k][qq] + red[1][k][qq] + red[2][k][qq] + red[3][k][qq] + pb[k];
    clT[(blockIdx.x * 64 + qq) * 32 + k] = f2bf(s);
  }
  // zero the k in [16,32) pad: 64 q-rows x 16 ushorts = 2 KB per block
  if (t < 128){
    uint4 zv = {0u, 0u, 0u, 0u};
    int qq = t >> 1, half = t & 1;
    *reinterpret_cast<uint4*>(&clT[(blockIdx.x * 64 + qq) * 32 + 16 + half * 8]) = zv;
  }
}

// ---------- fused hat GEMM via MFMA; all hot-loop addressing loop-invariant.
// out[c,q] = sum_p fs[c,p] * tanh(sum_k v[k,p]*u[k,q])
// grid 512 flat (XCD-swizzled), block 512 (8 waves). Tile: C=256 x 32 q, 2 blocks/CU.
__global__ __launch_bounds__(512, 4) void k_hat(
    const unsigned short* __restrict__ fs1, const unsigned short* __restrict__ fs2,
    const unsigned short* __restrict__ clT1, const unsigned short* __restrict__ clT2,
    float* __restrict__ hat1, float* __restrict__ hat2){
  const int t = threadIdx.x;
  // XCD swizzle: 2 XCDs per (n,i); 2MB fs panel fits each XCD's 4MB L2
  const int bid = blockIdx.x;
  const int xcd = bid & 7, slot = bid >> 3;    // slot 0..63
  const int z = xcd >> 1;                      // 0..3 -> (n,i)
  const int n = z & 1, i = z >> 1;
  const int x = slot * 2 + (xcd & 1);          // 0..127 q-tile
  const int q0 = x * 32;

  const unsigned short* fs = (i ? fs2 : fs1) + n * C_CH * HW_SZ;
  const unsigned short* uT = (i ? clT1 : clT2) + n * 32 * HW_SZ;  // q-side [HW][32]
  const unsigned short* vT = (i ? clT2 : clT1) + n * 32 * HW_SZ;  // p-side [HW][32]
  float* out = (i ? hat2 : hat1) + n * C_CH * HW_SZ;

  __shared__ __align__(16) unsigned short fsA[2][C_CH * 64];  // 32KB each: [c][p swz]
  __shared__ __align__(16) unsigned short vB[2][64 * 32];     // 4KB each: [p][k0..31]
  __shared__ __align__(16) unsigned short aT[2][32 * 64];     // 4KB each: [q][p swz]

  const int wv = t >> 6, l = t & 63;
  const int g4 = l >> 4, lr16 = l & 15;      // d-gen (16x16)
  const int g2 = l >> 5, lr32 = l & 31;      // main (32x32)
  const int pfw = wv & 3, qfw = wv >> 2;

  // ---- one-time u fragment (B-op of d-gen), k-pad already zeroed in memory
  const bf16x8 ub = *reinterpret_cast<const bf16x8*>(&uT[(q0 + qfw * 16 + lr16) * 32 + g4 * 8]);

  f32x16 acc;
  #pragma unroll
  for (int r = 0; r < 16; ++r) acc[r] = 0.f;
  const f32x4 zz = {0.f, 0.f, 0.f, 0.f};

  // ---- per-thread byte offsets (computed ONCE; hot loop adds nothing)
  int fs_off[4];
  #pragma unroll
  for (int it = 0; it < 4; ++it){
    int d = it * 512 + t; int c = d >> 3, col = d & 7;
    fs_off[it] = c * (HW_SZ * 2) + ((col ^ (c & 7)) * 16);
  }
  const int vt_off = (t >> 2) * 64 + (t & 3) * 16;          // used by waves 0..3

  const char* fsb0 = (const char*)&fsA[0][0];
  const char* fsb1 = (const char*)&fsA[1][0];
  const char* vbb0 = (const char*)&vB[0][0];
  const char* vbb1 = (const char*)&vB[1][0];
  char* atb0 = (char*)&aT[0][0];
  char* atb1 = (char*)&aT[1][0];

  const int crow = wv * 32 + lr32;
  const unsigned afo = crow * 128 + ((g2 ^ (crow & 7)) << 4);          // ^ (ks<<5)
  const unsigned bqo = lr32 * 128 + ((g2 ^ (lr32 & 7)) << 4);          // ^ (ks<<5)
  const unsigned vbr = (pfw * 16 + lr16) * 64 + g4 * 16;
  const int qd = qfw * 16 + lr16;
  const unsigned atw = qd * 128 + (((pfw * 2 + (g4 >> 1)) ^ (qd & 7)) << 4) + (g4 & 1) * 8;

  auto stage_fs = [&](unsigned short* dstbase, const unsigned short* src){
    #pragma unroll
    for (int it = 0; it < 4; ++it)
      gload16((const char*)src + fs_off[it], dstbase + (it * 512 + wv * 64) * 8);
  };
  auto stage_v = [&](unsigned short* dstbase, const unsigned short* src){
    if (wv < 4)
      gload16((const char*)src + vt_off, dstbase + wv * 512);
  };
  auto dgen = [&](const char* vbB, char* atB){
    bf16x8 av = *reinterpret_cast<const bf16x8*>(vbB + vbr);
    f32x4 dv = __builtin_amdgcn_mfma_f32_16x16x32_bf16(av, ub, zz, 0, 0, 0);
    uint2 pk;
    pk.x = pack_bf2(tanh_fast(dv[0]), tanh_fast(dv[1]));
    pk.y = pack_bf2(tanh_fast(dv[2]), tanh_fast(dv[3]));
    *reinterpret_cast<uint2*>(atB + atw) = pk;
  };
  auto mmain = [&](const char* faB, const char* atB){
    #pragma unroll
    for (int ks = 0; ks < 4; ++ks){
      bf16x8 bq = *reinterpret_cast<const bf16x8*>(atB + (bqo ^ (unsigned)(ks << 5)));
      bf16x8 af = *reinterpret_cast<const bf16x8*>(faB + (afo ^ (unsigned)(ks << 5)));
      acc = __builtin_amdgcn_mfma_f32_32x32x16_bf16(af, bq, acc, 0, 0, 0);
    }
  };

  // ---- prologue: fs chunk0 -> fsA[0]; v chunks 0,1 -> vB[0],vB[1]; a(0) -> aT[0]
  stage_fs(fsA[0], fs);
  stage_v(vB[0], vT);
  stage_v(vB[1], vT + 2048);
  __syncthreads();
  dgen(vbb0, atb0);
  __syncthreads();

  const unsigned short* fsp = fs + 64;        // fs source for chunk k+1
  const unsigned short* vsp = vT + 2 * 2048;  // vT source for chunk k+2

  // ---- main loop: 64 chunks, unrolled x2 so buffer selection is compile-time
  for (int k2 = 0; k2 < 32; ++k2){
    {
      const int k = 2 * k2;                    // buf 0
      if (k < 63) stage_fs(fsA[1], fsp);
      if (k < 62) stage_v(vB[0], vsp);
      if (k < 63) dgen(vbb1, atb1);
      mmain(fsb0, atb0);
      fsp += 64; vsp += 2048;
      __syncthreads();
    }
    {
      const int k = 2 * k2 + 1;                // buf 1
      if (k < 63) stage_fs(fsA[0], fsp);
      if (k < 62) stage_v(vB[1], vsp);
      if (k < 63) dgen(vbb0, atb0);
      mmain(fsb1, atb1);
      fsp += 64; vsp += 2048;
      __syncthreads();
    }
  }

  // ---- store: 32x32 C-layout: col(=q)=lane&31, row(=c)=(reg&3)+8*(reg>>2)+4*(lane>>5)
  const int qcol = q0 + lr32;
  #pragma unroll
  for (int r = 0; r < 16; ++r){
    int c = wv * 32 + (r & 3) + 8 * (r >> 2) + 4 * g2;
    out[c * HW_SZ + qcol] = acc[r];
  }
}

// ---------- l2norm(channels) + residual + relu (IN-PLACE into hat) + stage-2 conv
__global__ void k_norm(float* __restrict__ hat1, float* __restrict__ hat2,
                       const float* __restrict__ f1, const float* __restrict__ f2,
                       const float* __restrict__ cw1, const float* __restrict__ cw2,
                       const float* __restrict__ cb1, const float* __restrict__ cb2,
                       float* __restrict__ cv2){
  const int i = blockIdx.z, n = blockIdx.y, t = threadIdx.x;
  const int ql = t & 63, cg = t >> 6;
  const int q = blockIdx.x * 64 + ql;
  float* hat = (i ? hat2 : hat1) + n * C_CH * HW_SZ;
  const float* f = (i ? f2 : f1) + n * C_CH * HW_SZ;
  __shared__ float ws[C_CH];
  __shared__ float red[4][72];
  __shared__ float invs[64];
  ws[t] = (i ? cw2 : cw1)[t];
  __syncthreads();
  float s = 0.f;
  #pragma unroll 8
  for (int c = cg * 64; c < cg * 64 + 64; ++c){ float h = hat[c * HW_SZ + q]; s += h * h; }
  red[cg][ql] = s; __syncthreads();
  if (t < 64){
    float ss = red[0][t] + red[1][t] + red[2][t] + red[3][t];
    invs[t] = 1.0f / fmaxf(sqrtf(ss), 1e-12f);
  }
  __syncthreads();
  const float inv = invs[ql];
  float ca = 0.f;
  #pragma unroll 8
  for (int c = cg * 64; c < cg * 64 + 64; ++c){
    float vv = fmaxf(hat[c * HW_SZ + q] * inv + f[c * HW_SZ + q], 0.0f);
    hat[c * HW_SZ + q] = vv;  // in-place: only this thread touches [c][q]
    ca += ws[c] * vv;
  }
  red[cg][ql] = ca; __syncthreads();
  if (t < 64){
    float ss = red[0][t] + red[1][t] + red[2][t] + red[3][t] + (i ? cb2[0] : cb1[0]);
    cv2[(i * 2 + n) * HW_SZ + blockIdx.x * 64 + t] = ss;
  }
}

// ---------- final: out_i = pr2_i * fp_i
__global__ void k_final(const float* __restrict__ fp1, const float* __restrict__ fp2,
                        const float* __restrict__ pr2, float* __restrict__ outp){
  const int i = blockIdx.z;
  const int idx4 = (blockIdx.x * 256 + threadIdx.x) * 4;
  const int n = idx4 >> 20;
  const int q = idx4 & (HW_SZ - 1);
  const float* fp = i ? fp2 : fp1;
  float4 vv = *reinterpret_cast<const float4*>(&fp[idx4]);
  float4 pp = *reinterpret_cast<const float4*>(&pr2[(i * 2 + n) * HW_SZ + q]);
  float4 o; o.x = vv.x * pp.x; o.y = vv.y * pp.y; o.z = vv.z * pp.z; o.w = vv.w * pp.w;
  *reinterpret_cast<float4*>(&outp[i * (C_CH * HW_SZ * N_B) + idx4]) = o;
}

extern "C" void kernel_launch(void* const* d_in, const int* in_sizes, int n_in,
                              void* d_out, int out_size, void* d_ws, size_t ws_size,
                              hipStream_t stream){
  const float* f1  = (const float*)d_in[0];
  const float* f2  = (const float*)d_in[1];
  const float* pw1 = (const float*)d_in[2];
  const float* pb1 = (const float*)d_in[3];
  const float* pw2 = (const float*)d_in[4];
  const float* pb2 = (const float*)d_in[5];
  const float* cw1 = (const float*)d_in[6];
  const float* cb1 = (const float*)d_in[7];
  const float* cw2 = (const float*)d_in[8];
  const float* cb2 = (const float*)d_in[9];
  float* ws = (float*)d_ws;
  // layout (float offsets): HAT doubles as FP (k_norm in-place, k_final reads it)
  float* HAT1 = ws;                                        // 2,097,152 floats
  float* HAT2 = ws + 2097152;
  unsigned short* FS1 = (unsigned short*)(ws + 4194304);   // bf16 [C][HW] per n
  unsigned short* FS2 = (unsigned short*)(ws + 5242880);
  unsigned short* CLT1 = (unsigned short*)(ws + 6291456);  // bf16 [HW][32] per n (131072 floats)
  unsigned short* CLT2 = (unsigned short*)(ws + 6422528);
  float* CV1  = ws + 6553600;
  float* PR1  = ws + 6569984;
  float* CV2  = ws + 6586368;
  float* PR2  = ws + 6602752;                              // end 6,619,136 floats ~= 25.2 MiB
  float* outp = (float*)d_out;

  k_conv1   <<<dim3(64, 2, 2), 256, 0, stream>>>(f1, f2, cw1, cw2, cb1, cb2, CV1);
  k_softmax <<<4, 256, 0, stream>>>(CV1, PR1);
  k_scale_cl<<<dim3(64, 2, 2), 256, 0, stream>>>(f1, f2, PR1, pw1, pw2, pb1, pb2,
                                                 FS1, FS2, CLT1, CLT2);
  k_hat     <<<512, 512, 0, stream>>>(FS1, FS2, CLT1, CLT2, HAT1, HAT2);
  k_norm    <<<dim3(64, 2, 2), 256, 0, stream>>>(HAT1, HAT2, f1, f2, cw1, cw2, cb1, cb2, CV2);
  k_softmax <<<4, 256, 0, stream>>>(CV2, PR2);
  k_final   <<<dim3(2048, 1, 2), 256, 0, stream>>>(HAT1, HAT2, PR2, outp);
}

// Round 7
// 118.627 us; speedup vs baseline: 2.7715x; 1.0598x over previous
//
#include <hip/hip_runtime.h>
#include <hip/hip_bf16.h>
#include <math.h>

#define N_B 2
#define C_CH 256
#define HW_SZ 4096
#define CL_CH 16

typedef __bf16 bf16x8 __attribute__((ext_vector_type(8)));
typedef float f32x4 __attribute__((ext_vector_type(4)));
typedef float f32x16 __attribute__((ext_vector_type(16)));

__device__ __forceinline__ unsigned short f2bf(float x){
  __hip_bfloat16 b = __float2bfloat16(x);   // RTNE
  return *reinterpret_cast<unsigned short*>(&b);
}
__device__ __forceinline__ unsigned int pack_bf2(float a, float b){
  return (unsigned int)f2bf(a) | ((unsigned int)f2bf(b) << 16);
}
// tanh, NaN-safe: 1 - 2/(1+e^{2x})
__device__ __forceinline__ float tanh_fast(float x){
  float e = __expf(2.0f * x);
  return 1.0f - 2.0f / (1.0f + e);
}
// async global->LDS, 16B per lane; dst must be wave-uniform base (+lane*16 implicit)
__device__ __forceinline__ void gload16(const void* gsrc, void* lds_dst){
  __builtin_amdgcn_global_load_lds(
      (const __attribute__((address_space(1))) unsigned int*)gsrc,
      (__attribute__((address_space(3))) unsigned int*)lds_dst, 16, 0, 0);
}

// ---------- Stage-1 conv (C->1)
__global__ void k_conv1(const float* __restrict__ f1, const float* __restrict__ f2,
                        const float* __restrict__ w1, const float* __restrict__ w2,
                        const float* __restrict__ b1, const float* __restrict__ b2,
                        float* __restrict__ cv){
  const int i = blockIdx.z, n = blockIdx.y, t = threadIdx.x;
  const int ql = t & 63, cg = t >> 6;
  const int q = blockIdx.x * 64 + ql;
  const float* f = (i ? f2 : f1) + n * C_CH * HW_SZ;
  const float* w = i ? w2 : w1;
  __shared__ float ws[C_CH];
  __shared__ float red[4][72];
  ws[t] = w[t];
  __syncthreads();
  float acc = 0.f;
  #pragma unroll 8
  for (int c = cg * 64; c < cg * 64 + 64; ++c)
    acc += f[c * HW_SZ + q] * ws[c];
  red[cg][ql] = acc;
  __syncthreads();
  if (t < 64){
    float s = red[0][t] + red[1][t] + red[2][t] + red[3][t] + (i ? b2[0] : b1[0]);
    cv[(i * 2 + n) * HW_SZ + blockIdx.x * 64 + t] = s;
  }
}

// ---------- softmax over 4096 per row; grid(4) block 256
__global__ void k_softmax(const float* __restrict__ cv, float* __restrict__ pr){
  const int r = blockIdx.x, t = threadIdx.x;
  const float* x = cv + r * HW_SZ;
  float* y = pr + r * HW_SZ;
  __shared__ float red[256];
  float v[16];
  float m = -1e30f;
  #pragma unroll
  for (int j = 0; j < 16; j++){ v[j] = x[j * 256 + t]; m = fmaxf(m, v[j]); }
  red[t] = m; __syncthreads();
  for (int s = 128; s > 0; s >>= 1){ if (t < s) red[t] = fmaxf(red[t], red[t + s]); __syncthreads(); }
  m = red[0]; __syncthreads();
  float sum = 0.f;
  #pragma unroll
  for (int j = 0; j < 16; j++){ v[j] = __expf(v[j] - m); sum += v[j]; }
  red[t] = sum; __syncthreads();
  for (int s = 128; s > 0; s >>= 1){ if (t < s) red[t] += red[t + s]; __syncthreads(); }
  const float inv = 1.0f / red[0];
  #pragma unroll
  for (int j = 0; j < 16; j++) y[j * 256 + t] = v[j] * inv;
}

// ---------- fs_i = bf16(pr_i * f_i) ; clT_i[q][0..15] = bf16(pw_i @ (pr*f) + pb_i),
// clT rows are 32 wide with k in [16,32) zeroed (branch-free MFMA fragments in k_hat)
__global__ void k_scale_cl(const float* __restrict__ f1, const float* __restrict__ f2,
                           const float* __restrict__ pr,
                           const float* __restrict__ pw1, const float* __restrict__ pw2,
                           const float* __restrict__ pb1, const float* __restrict__ pb2,
                           unsigned short* __restrict__ fs1, unsigned short* __restrict__ fs2,
                           unsigned short* __restrict__ clT1, unsigned short* __restrict__ clT2){
  const int i = blockIdx.z, n = blockIdx.y, t = threadIdx.x;
  const int ql = t & 63, cg = t >> 6;
  const int q = blockIdx.x * 64 + ql;
  const float* f = (i ? f2 : f1) + n * C_CH * HW_SZ;
  unsigned short* fs = (i ? fs2 : fs1) + n * C_CH * HW_SZ;
  unsigned short* clT = (i ? clT2 : clT1) + n * 32 * HW_SZ;
  const float* pw = i ? pw2 : pw1;
  const float* pb = i ? pb2 : pb1;
  __shared__ float wls[CL_CH * C_CH];
  __shared__ float red[4][CL_CH][66];
  #pragma unroll
  for (int j = 0; j < 16; j++) wls[j * 256 + t] = pw[j * 256 + t];
  __syncthreads();
  const float p = pr[(i * 2 + n) * HW_SZ + q];
  float acc[16];
  #pragma unroll
  for (int k = 0; k < 16; k++) acc[k] = 0.f;
  for (int c = cg * 64; c < cg * 64 + 64; ++c){
    float vv = f[c * HW_SZ + q] * p;
    fs[c * HW_SZ + q] = f2bf(vv);
    #pragma unroll
    for (int k = 0; k < 16; k++) acc[k] += wls[k * 256 + c] * vv;
  }
  #pragma unroll
  for (int k = 0; k < 16; k++) red[cg][k][ql] = acc[k];
  __syncthreads();
  #pragma unroll
  for (int j = 0; j < 4; j++){
    int e = j * 256 + t; int k = e >> 6, qq = e & 63;
    float s = red[0][k][qq] + red[1][k][qq] + red[2][k][qq] + red[3][k][qq] + pb[k];
    clT[(blockIdx.x * 64 + qq) * 32 + k] = f2bf(s);
  }
  // zero the k in [16,32) pad
  if (t < 128){
    uint4 zv = {0u, 0u, 0u, 0u};
    int qq = t >> 1, half = t & 1;
    *reinterpret_cast<uint4*>(&clT[(blockIdx.x * 64 + qq) * 32 + 16 + half * 8]) = zv;
  }
}

// ---------- fused hat GEMM via MFMA. Q=128 tile, split-K over p-halves.
// out[c,q] = sum_p fs[c,p] * tanh(sum_k v[k,p]*u[k,q])
// grid 256 (XCD-swizzled -> (n,i,qtile,phalf)), block 512 (8 waves), 1 blk/CU.
// Per chunk (BK=64): stage k+1 (async DMA, NOT drained at mid-barrier) ||
// dgen(k) -> lgkmcnt(0)+s_barrier -> mmain(k) -> __syncthreads (drain).
__global__ __launch_bounds__(512, 2) void k_hat(
    const unsigned short* __restrict__ fs1, const unsigned short* __restrict__ fs2,
    const unsigned short* __restrict__ clT1, const unsigned short* __restrict__ clT2,
    float* __restrict__ hat1, float* __restrict__ hat2,
    float* __restrict__ pt1, float* __restrict__ pt2){
  const int t = threadIdx.x;
  const int bid = blockIdx.x;
  const int xcd = bid & 7, slot = bid >> 3;
  const int z = xcd >> 1;                    // 0..3 -> (n,i); 2 XCDs per (n,i)
  const int n = z & 1, i = z >> 1;
  const int x = slot * 2 + (xcd & 1);        // 0..63
  const int qt = x >> 1, ph = x & 1;         // 32 q-tiles x 2 p-halves
  const int q0 = qt * 128;
  const int pbase = ph * 2048;

  const unsigned short* fs = (i ? fs2 : fs1) + n * C_CH * HW_SZ;
  const unsigned short* uT = (i ? clT1 : clT2) + n * 32 * HW_SZ;  // q-side [HW][32]
  const unsigned short* vT = (i ? clT2 : clT1) + n * 32 * HW_SZ;  // p-side [HW][32]
  float* out = (ph ? (i ? pt2 : pt1) : (i ? hat2 : hat1)) + n * C_CH * HW_SZ;

  __shared__ __align__(16) unsigned short fsA[2][C_CH * 64];  // 32KB each: [c][p swz]
  __shared__ __align__(16) unsigned short vB[2][64 * 32];     // 4KB each: [p][k swz]
  __shared__ __align__(16) unsigned short aT[128 * 64];       // 16KB: [q][p swz]

  const int wv = t >> 6, l = t & 63;
  const int g4 = l >> 4, lr16 = l & 15;      // d-gen (16x16)
  const int g2 = l >> 5, lr32 = l & 31;      // main (32x32)

  // dgen: wave wv -> pf = wv&3, q-frags qfb..qfb+3 (16-wide)
  const int pfw = wv & 3;
  const int qfb = (wv >> 2) * 4;
  // mmain: wave wv -> c-frags {2(wv&3), 2(wv&3)+1}, q-frags(32) {2(wv>>2), 2(wv>>2)+1}
  const int cblk = wv & 3, qblk = wv >> 2;

  // ---- one-time u fragments (k-pad zeroed at source)
  bf16x8 ub0 = *reinterpret_cast<const bf16x8*>(&uT[(q0 + (qfb + 0) * 16 + lr16) * 32 + g4 * 8]);
  bf16x8 ub1 = *reinterpret_cast<const bf16x8*>(&uT[(q0 + (qfb + 1) * 16 + lr16) * 32 + g4 * 8]);
  bf16x8 ub2 = *reinterpret_cast<const bf16x8*>(&uT[(q0 + (qfb + 2) * 16 + lr16) * 32 + g4 * 8]);
  bf16x8 ub3 = *reinterpret_cast<const bf16x8*>(&uT[(q0 + (qfb + 3) * 16 + lr16) * 32 + g4 * 8]);

  f32x16 acc00, acc01, acc10, acc11;
  #pragma unroll
  for (int r = 0; r < 16; ++r){ acc00[r] = 0.f; acc01[r] = 0.f; acc10[r] = 0.f; acc11[r] = 0.f; }
  const f32x4 zz = {0.f, 0.f, 0.f, 0.f};

  // ---- per-thread byte offsets (computed once)
  // fsA: LDS chunk d holds src col16 u = (d&7) ^ (c&7) ^ (((c>>3)&1)<<2), c = d>>3
  int fs_src[4];
  #pragma unroll
  for (int it = 0; it < 4; ++it){
    int d = it * 512 + t; int c = d >> 3, s = d & 7;
    int u = s ^ (c & 7) ^ (((c >> 3) & 1) << 2);
    fs_src[it] = c * (HW_SZ * 2) + u * 16;
  }
  // vB: LDS chunk j holds src k-unit u = (j&3) ^ (p&3) ^ ((p>>2)&3), p = j>>2
  int vt_src;
  {
    int j = t & 255; int p = j >> 2, s = j & 3;
    int u = s ^ (p & 3) ^ ((p >> 2) & 3);
    vt_src = p * 64 + u * 16;
  }
  // dgen vB read: row p = pfw*16+lr16, unit g4
  int vbr;
  {
    int p = pfw * 16 + lr16;
    vbr = p * 64 + ((g4 ^ (p & 3) ^ ((p >> 2) & 3)) << 4);
  }
  // dgen aT write: q = qfb*16+lr16 (+16 per j), chunk = pfw*2+(g4>>1), swz j-invariant
  unsigned atw0;
  {
    int qd = qfb * 16 + lr16;
    int sw = (pfw * 2 + (g4 >> 1)) ^ (qd & 7) ^ (((qd >> 3) & 1) << 2);
    atw0 = qd * 128 + sw * 16 + (g4 & 1) * 8;
  }
  // mmain reads: chunk = 2ks + g2 -> byte ^= ks<<5
  unsigned afo[2], bqo[2];
  #pragma unroll
  for (int cfi = 0; cfi < 2; ++cfi){
    int crow = cblk * 64 + cfi * 32 + lr32;
    afo[cfi] = crow * 128 + ((g2 ^ (crow & 7) ^ (((crow >> 3) & 1) << 2)) << 4);
  }
  #pragma unroll
  for (int qq = 0; qq < 2; ++qq){
    int qrow = qblk * 64 + qq * 32 + lr32;
    bqo[qq] = qrow * 128 + ((g2 ^ (qrow & 7) ^ (((qrow >> 3) & 1) << 2)) << 4);
  }

  const char* fsb[2] = {(const char*)&fsA[0][0], (const char*)&fsA[1][0]};
  const char* vbb[2] = {(const char*)&vB[0][0], (const char*)&vB[1][0]};
  char* atb = (char*)&aT[0];

  auto stage_fs = [&](unsigned short* dstbase, int p0){
    const char* src = (const char*)fs + p0 * 2;
    #pragma unroll
    for (int it = 0; it < 4; ++it)
      gload16(src + fs_src[it], dstbase + (it * 512 + wv * 64) * 8);
  };
  auto stage_v = [&](unsigned short* dstbase, int p0){
    if (wv < 4)
      gload16((const char*)vT + p0 * 64 + vt_src, dstbase + wv * 512);
  };
  auto dgen = [&](const char* vbB){
    bf16x8 av = *reinterpret_cast<const bf16x8*>(vbB + vbr);
    f32x4 d0 = __builtin_amdgcn_mfma_f32_16x16x32_bf16(av, ub0, zz, 0, 0, 0);
    f32x4 d1 = __builtin_amdgcn_mfma_f32_16x16x32_bf16(av, ub1, zz, 0, 0, 0);
    f32x4 d2 = __builtin_amdgcn_mfma_f32_16x16x32_bf16(av, ub2, zz, 0, 0, 0);
    f32x4 d3 = __builtin_amdgcn_mfma_f32_16x16x32_bf16(av, ub3, zz, 0, 0, 0);
    uint2 pk;
    pk.x = pack_bf2(tanh_fast(d0[0]), tanh_fast(d0[1]));
    pk.y = pack_bf2(tanh_fast(d0[2]), tanh_fast(d0[3]));
    *reinterpret_cast<uint2*>(atb + atw0) = pk;
    pk.x = pack_bf2(tanh_fast(d1[0]), tanh_fast(d1[1]));
    pk.y = pack_bf2(tanh_fast(d1[2]), tanh_fast(d1[3]));
    *reinterpret_cast<uint2*>(atb + atw0 + 2048) = pk;
    pk.x = pack_bf2(tanh_fast(d2[0]), tanh_fast(d2[1]));
    pk.y = pack_bf2(tanh_fast(d2[2]), tanh_fast(d2[3]));
    *reinterpret_cast<uint2*>(atb + atw0 + 4096) = pk;
    pk.x = pack_bf2(tanh_fast(d3[0]), tanh_fast(d3[1]));
    pk.y = pack_bf2(tanh_fast(d3[2]), tanh_fast(d3[3]));
    *reinterpret_cast<uint2*>(atb + atw0 + 6144) = pk;
  };
  auto mmain = [&](const char* faB){
    #pragma unroll
    for (int ks = 0; ks < 4; ++ks){
      unsigned kx = (unsigned)(ks << 5);
      bf16x8 a0 = *reinterpret_cast<const bf16x8*>(faB + (afo[0] ^ kx));
      bf16x8 a1 = *reinterpret_cast<const bf16x8*>(faB + (afo[1] ^ kx));
      bf16x8 b0 = *reinterpret_cast<const bf16x8*>(atb + (bqo[0] ^ kx));
      bf16x8 b1 = *reinterpret_cast<const bf16x8*>(atb + (bqo[1] ^ kx));
      acc00 = __builtin_amdgcn_mfma_f32_32x32x16_bf16(a0, b0, acc00, 0, 0, 0);
      acc01 = __builtin_amdgcn_mfma_f32_32x32x16_bf16(a0, b1, acc01, 0, 0, 0);
      acc10 = __builtin_amdgcn_mfma_f32_32x32x16_bf16(a1, b0, acc10, 0, 0, 0);
      acc11 = __builtin_amdgcn_mfma_f32_32x32x16_bf16(a1, b1, acc11, 0, 0, 0);
    }
  };

  // ---- prologue: chunk 0 into buf 0
  stage_fs(fsA[0], pbase);
  stage_v(vB[0], pbase);
  __syncthreads();

  // ---- main loop: 32 chunks, unrolled x2 (compile-time buffers).
  // Final iteration's prefetch overreads by <=64 cols into adjacent ws buffers (harmless).
  #pragma unroll 1
  for (int k2 = 0; k2 < 16; ++k2){
    {
      const int p0n = pbase + (2 * k2 + 1) * 64;
      stage_fs(fsA[1], p0n);
      stage_v(vB[1], p0n);
      dgen(vbb[0]);
      asm volatile("s_waitcnt lgkmcnt(0)" ::: "memory");
      __builtin_amdgcn_sched_barrier(0);
      __builtin_amdgcn_s_barrier();           // aT visible; DMA still in flight
      mmain(fsb[0]);
      __syncthreads();                        // drains vmcnt (latency already covered)
    }
    {
      const int p0n = pbase + (2 * k2 + 2) * 64;
      stage_fs(fsA[0], p0n);
      stage_v(vB[0], p0n);
      dgen(vbb[1]);
      asm volatile("s_waitcnt lgkmcnt(0)" ::: "memory");
      __builtin_amdgcn_sched_barrier(0);
      __builtin_amdgcn_s_barrier();
      mmain(fsb[1]);
      __syncthreads();
    }
  }

  // ---- store: 32x32 C-layout: col(=q)=lane&31, row(=c)=(reg&3)+8*(reg>>2)+4*(lane>>5)
  #pragma unroll
  for (int r = 0; r < 16; ++r){
    int cr = (r & 3) + 8 * (r >> 2) + 4 * g2;
    out[(cblk * 64 + 0 * 32 + cr) * HW_SZ + q0 + qblk * 64 + 0 * 32 + lr32] = acc00[r];
    out[(cblk * 64 + 0 * 32 + cr) * HW_SZ + q0 + qblk * 64 + 1 * 32 + lr32] = acc01[r];
    out[(cblk * 64 + 1 * 32 + cr) * HW_SZ + q0 + qblk * 64 + 0 * 32 + lr32] = acc10[r];
    out[(cblk * 64 + 1 * 32 + cr) * HW_SZ + q0 + qblk * 64 + 1 * 32 + lr32] = acc11[r];
  }
}

// ---------- l2norm(channels) of (part0+part1) + residual + relu (in-place into part0) + stage-2 conv
__global__ void k_norm(float* __restrict__ hat1, float* __restrict__ hat2,
                       const float* __restrict__ pt1, const float* __restrict__ pt2,
                       const float* __restrict__ f1, const float* __restrict__ f2,
                       const float* __restrict__ cw1, const float* __restrict__ cw2,
                       const float* __restrict__ cb1, const float* __restrict__ cb2,
                       float* __restrict__ cv2){
  const int i = blockIdx.z, n = blockIdx.y, t = threadIdx.x;
  const int ql = t & 63, cg = t >> 6;
  const int q = blockIdx.x * 64 + ql;
  float* hat = (i ? hat2 : hat1) + n * C_CH * HW_SZ;
  const float* pt = (i ? pt2 : pt1) + n * C_CH * HW_SZ;
  const float* f = (i ? f2 : f1) + n * C_CH * HW_SZ;
  __shared__ float ws[C_CH];
  __shared__ float red[4][72];
  __shared__ float invs[64];
  ws[t] = (i ? cw2 : cw1)[t];
  __syncthreads();
  float s = 0.f;
  #pragma unroll 8
  for (int c = cg * 64; c < cg * 64 + 64; ++c){
    float h = hat[c * HW_SZ + q] + pt[c * HW_SZ + q];
    s += h * h;
  }
  red[cg][ql] = s; __syncthreads();
  if (t < 64){
    float ss = red[0][t] + red[1][t] + red[2][t] + red[3][t];
    invs[t] = 1.0f / fmaxf(sqrtf(ss), 1e-12f);
  }
  __syncthreads();
  const float inv = invs[ql];
  float ca = 0.f;
  #pragma unroll 8
  for (int c = cg * 64; c < cg * 64 + 64; ++c){
    float h = hat[c * HW_SZ + q] + pt[c * HW_SZ + q];
    float vv = fmaxf(h * inv + f[c * HW_SZ + q], 0.0f);
    hat[c * HW_SZ + q] = vv;  // in-place: only this thread touches [c][q]
    ca += ws[c] * vv;
  }
  red[cg][ql] = ca; __syncthreads();
  if (t < 64){
    float ss = red[0][t] + red[1][t] + red[2][t] + red[3][t] + (i ? cb2[0] : cb1[0]);
    cv2[(i * 2 + n) * HW_SZ + blockIdx.x * 64 + t] = ss;
  }
}

// ---------- final: out_i = pr2_i * fp_i
__global__ void k_final(const float* __restrict__ fp1, const float* __restrict__ fp2,
                        const float* __restrict__ pr2, float* __restrict__ outp){
  const int i = blockIdx.z;
  const int idx4 = (blockIdx.x * 256 + threadIdx.x) * 4;
  const int n = idx4 >> 20;
  const int q = idx4 & (HW_SZ - 1);
  const float* fp = i ? fp2 : fp1;
  float4 vv = *reinterpret_cast<const float4*>(&fp[idx4]);
  float4 pp = *reinterpret_cast<const float4*>(&pr2[(i * 2 + n) * HW_SZ + q]);
  float4 o; o.x = vv.x * pp.x; o.y = vv.y * pp.y; o.z = vv.z * pp.z; o.w = vv.w * pp.w;
  *reinterpret_cast<float4*>(&outp[i * (C_CH * HW_SZ * N_B) + idx4]) = o;
}

extern "C" void kernel_launch(void* const* d_in, const int* in_sizes, int n_in,
                              void* d_out, int out_size, void* d_ws, size_t ws_size,
                              hipStream_t stream){
  const float* f1  = (const float*)d_in[0];
  const float* f2  = (const float*)d_in[1];
  const float* pw1 = (const float*)d_in[2];
  const float* pb1 = (const float*)d_in[3];
  const float* pw2 = (const float*)d_in[4];
  const float* pb2 = (const float*)d_in[5];
  const float* cw1 = (const float*)d_in[6];
  const float* cb1 = (const float*)d_in[7];
  const float* cw2 = (const float*)d_in[8];
  const float* cb2 = (const float*)d_in[9];
  float* ws = (float*)d_ws;
  // layout (float offsets): HAT = part0 (doubles as FP), PT = part1
  float* HAT1 = ws;                                        // 2,097,152 floats each
  float* HAT2 = ws + 2097152;
  float* PT1  = ws + 4194304;
  float* PT2  = ws + 6291456;
  unsigned short* FS1 = (unsigned short*)(ws + 8388608);   // bf16 [C][HW] per n
  unsigned short* FS2 = (unsigned short*)(ws + 9437184);
  unsigned short* CLT1 = (unsigned short*)(ws + 10485760); // bf16 [HW][32] per n
  unsigned short* CLT2 = (unsigned short*)(ws + 10616832);
  float* CV1  = ws + 10747904;
  float* PR1  = ws + 10764288;
  float* CV2  = ws + 10780672;
  float* PR2  = ws + 10797056;                             // end 10,813,440 floats ~= 43.3 MiB
  float* outp = (float*)d_out;

  k_conv1   <<<dim3(64, 2, 2), 256, 0, stream>>>(f1, f2, cw1, cw2, cb1, cb2, CV1);
  k_softmax <<<4, 256, 0, stream>>>(CV1, PR1);
  k_scale_cl<<<dim3(64, 2, 2), 256, 0, stream>>>(f1, f2, PR1, pw1, pw2, pb1, pb2,
                                                 FS1, FS2, CLT1, CLT2);
  k_hat     <<<256, 512, 0, stream>>>(FS1, FS2, CLT1, CLT2, HAT1, HAT2, PT1, PT2);
  k_norm    <<<dim3(64, 2, 2), 256, 0, stream>>>(HAT1, HAT2, PT1, PT2, f1, f2,
                                                 cw1, cw2, cb1, cb2, CV2);
  k_softmax <<<4, 256, 0, stream>>>(CV2, PR2);
  k_final   <<<dim3(2048, 1, 2), 256, 0, stream>>>(HAT1, HAT2, PR2, outp);
}

// Round 8
// 103.863 us; speedup vs baseline: 3.1654x; 1.1421x over previous
//
#include <hip/hip_runtime.h>
#include <hip/hip_bf16.h>
#include <math.h>

#define N_B 2
#define C_CH 256
#define HW_SZ 4096
#define CL_CH 16

typedef __bf16 bf16x8 __attribute__((ext_vector_type(8)));
typedef float f32x4 __attribute__((ext_vector_type(4)));
typedef float f32x16 __attribute__((ext_vector_type(16)));

__device__ __forceinline__ unsigned short f2bf(float x){
  __hip_bfloat16 b = __float2bfloat16(x);   // RTNE
  return *reinterpret_cast<unsigned short*>(&b);
}
// packed f32x2 -> bf16x2 (single v_cvt_pk_bf16_f32)
__device__ __forceinline__ unsigned int cvtpk(float a, float b){
  unsigned int r;
  asm("v_cvt_pk_bf16_f32 %0, %1, %2" : "=v"(r) : "v"(a), "v"(b));
  return r;
}
// tanh = 1 - 2*rcp(1+e^{2x}); NaN-safe at +-inf; rcp err ~1e-7 (<< bf16 ulp)
__device__ __forceinline__ float tanh_fast(float x){
  float e = __expf(2.0f * x);               // v_mul + v_mul + v_exp
  return fmaf(-2.0f, __builtin_amdgcn_rcpf(1.0f + e), 1.0f);
}
// async global->LDS, 16B per lane; dst must be wave-uniform base (+lane*16 implicit)
__device__ __forceinline__ void gload16(const void* gsrc, void* lds_dst){
  __builtin_amdgcn_global_load_lds(
      (const __attribute__((address_space(1))) unsigned int*)gsrc,
      (__attribute__((address_space(3))) unsigned int*)lds_dst, 16, 0, 0);
}

// ---------- Stage-1 conv (C->1)
__global__ void k_conv1(const float* __restrict__ f1, const float* __restrict__ f2,
                        const float* __restrict__ w1, const float* __restrict__ w2,
                        const float* __restrict__ b1, const float* __restrict__ b2,
                        float* __restrict__ cv){
  const int i = blockIdx.z, n = blockIdx.y, t = threadIdx.x;
  const int ql = t & 63, cg = t >> 6;
  const int q = blockIdx.x * 64 + ql;
  const float* f = (i ? f2 : f1) + n * C_CH * HW_SZ;
  const float* w = i ? w2 : w1;
  __shared__ float ws[C_CH];
  __shared__ float red[4][72];
  ws[t] = w[t];
  __syncthreads();
  float acc = 0.f;
  #pragma unroll 8
  for (int c = cg * 64; c < cg * 64 + 64; ++c)
    acc += f[c * HW_SZ + q] * ws[c];
  red[cg][ql] = acc;
  __syncthreads();
  if (t < 64){
    float s = red[0][t] + red[1][t] + red[2][t] + red[3][t] + (i ? b2[0] : b1[0]);
    cv[(i * 2 + n) * HW_SZ + blockIdx.x * 64 + t] = s;
  }
}

// ---------- softmax over 4096 per row; grid(4) block 256
__global__ void k_softmax(const float* __restrict__ cv, float* __restrict__ pr){
  const int r = blockIdx.x, t = threadIdx.x;
  const float* x = cv + r * HW_SZ;
  float* y = pr + r * HW_SZ;
  __shared__ float red[256];
  float v[16];
  float m = -1e30f;
  #pragma unroll
  for (int j = 0; j < 16; j++){ v[j] = x[j * 256 + t]; m = fmaxf(m, v[j]); }
  red[t] = m; __syncthreads();
  for (int s = 128; s > 0; s >>= 1){ if (t < s) red[t] = fmaxf(red[t], red[t + s]); __syncthreads(); }
  m = red[0]; __syncthreads();
  float sum = 0.f;
  #pragma unroll
  for (int j = 0; j < 16; j++){ v[j] = __expf(v[j] - m); sum += v[j]; }
  red[t] = sum; __syncthreads();
  for (int s = 128; s > 0; s >>= 1){ if (t < s) red[t] += red[t + s]; __syncthreads(); }
  const float inv = 1.0f / red[0];
  #pragma unroll
  for (int j = 0; j < 16; j++) y[j * 256 + t] = v[j] * inv;
}

// ---------- fs_i = bf16(pr_i * f_i) ; clT_i[q][0..15] = bf16(pw_i @ (pr*f) + pb_i),
// clT rows are 32 wide with k in [16,32) zeroed (branch-free MFMA fragments in k_hat)
__global__ void k_scale_cl(const float* __restrict__ f1, const float* __restrict__ f2,
                           const float* __restrict__ pr,
                           const float* __restrict__ pw1, const float* __restrict__ pw2,
                           const float* __restrict__ pb1, const float* __restrict__ pb2,
                           unsigned short* __restrict__ fs1, unsigned short* __restrict__ fs2,
                           unsigned short* __restrict__ clT1, unsigned short* __restrict__ clT2){
  const int i = blockIdx.z, n = blockIdx.y, t = threadIdx.x;
  const int ql = t & 63, cg = t >> 6;
  const int q = blockIdx.x * 64 + ql;
  const float* f = (i ? f2 : f1) + n * C_CH * HW_SZ;
  unsigned short* fs = (i ? fs2 : fs1) + n * C_CH * HW_SZ;
  unsigned short* clT = (i ? clT2 : clT1) + n * 32 * HW_SZ;
  const float* pw = i ? pw2 : pw1;
  const float* pb = i ? pb2 : pb1;
  __shared__ float wls[CL_CH * C_CH];
  __shared__ float red[4][CL_CH][66];
  #pragma unroll
  for (int j = 0; j < 16; j++) wls[j * 256 + t] = pw[j * 256 + t];
  __syncthreads();
  const float p = pr[(i * 2 + n) * HW_SZ + q];
  float acc[16];
  #pragma unroll
  for (int k = 0; k < 16; k++) acc[k] = 0.f;
  for (int c = cg * 64; c < cg * 64 + 64; ++c){
    float vv = f[c * HW_SZ + q] * p;
    fs[c * HW_SZ + q] = f2bf(vv);
    #pragma unroll
    for (int k = 0; k < 16; k++) acc[k] += wls[k * 256 + c] * vv;
  }
  #pragma unroll
  for (int k = 0; k < 16; k++) red[cg][k][ql] = acc[k];
  __syncthreads();
  #pragma unroll
  for (int j = 0; j < 4; j++){
    int e = j * 256 + t; int k = e >> 6, qq = e & 63;
    float s = red[0][k][qq] + red[1][k][qq] + red[2][k][qq] + red[3][k][qq] + pb[k];
    clT[(blockIdx.x * 64 + qq) * 32 + k] = f2bf(s);
  }
  // zero the k in [16,32) pad
  if (t < 128){
    uint4 zv = {0u, 0u, 0u, 0u};
    int qq = t >> 1, half = t & 1;
    *reinterpret_cast<uint4*>(&clT[(blockIdx.x * 64 + qq) * 32 + 16 + half * 8]) = zv;
  }
}

// ---------- fused hat GEMM via MFMA. C=256 x Q=64 tile, split-K over p-halves.
// out[c,q] = sum_p fs[c,p] * tanh(sum_k v[k,p]*u[k,q])
// grid 512 (XCD-swizzled -> (n,i,qtile,phalf)), block 512 (8 waves), LDS 80KB -> 2 blk/CU.
__global__ __launch_bounds__(512, 4) void k_hat(
    const unsigned short* __restrict__ fs1, const unsigned short* __restrict__ fs2,
    const unsigned short* __restrict__ clT1, const unsigned short* __restrict__ clT2,
    float* __restrict__ hat1, float* __restrict__ hat2,
    float* __restrict__ pt1, float* __restrict__ pt2){
  const int t = threadIdx.x;
  const int bid = blockIdx.x;
  const int xcd = bid & 7, slot = bid >> 3;  // slot 0..63
  const int z = xcd >> 1;                    // 0..3 -> (n,i); 2 XCDs per (n,i)
  const int n = z & 1, i = z >> 1;
  const int x = slot * 2 + (xcd & 1);        // 0..127
  const int qt = x >> 1, ph = x & 1;         // 64 q-tiles x 2 p-halves
  const int q0 = qt * 64;
  const int pbase = ph * 2048;

  const unsigned short* fs = (i ? fs2 : fs1) + n * C_CH * HW_SZ;
  const unsigned short* uT = (i ? clT1 : clT2) + n * 32 * HW_SZ;  // q-side [HW][32]
  const unsigned short* vT = (i ? clT2 : clT1) + n * 32 * HW_SZ;  // p-side [HW][32]
  float* out = (ph ? (i ? pt2 : pt1) : (i ? hat2 : hat1)) + n * C_CH * HW_SZ;

  __shared__ __align__(16) unsigned short fsA[2][C_CH * 64];  // 32KB each: [c][p swz]
  __shared__ __align__(16) unsigned short vB[2][64 * 32];     // 4KB each: [p][k swz]
  __shared__ __align__(16) unsigned short aT[64 * 64];        // 8KB: [q][p swz]

  const int wv = t >> 6, l = t & 63;
  const int g4 = l >> 4, lr16 = l & 15;      // d-gen (16x16)
  const int g2 = l >> 5, lr32 = l & 31;      // main (32x32)

  // dgen: wave wv -> p-frag pfw = wv&3; q-frags qf0, qf0+1 (16-wide each)
  const int pfw = wv & 3;
  const int qf0 = (wv >> 2) * 2;
  // mmain: wave wv -> c rows [cblk*64, +64), q cols [qblk*32, +32)
  const int cblk = wv & 3, qblk = wv >> 2;

  // ---- one-time u fragments (k-pad zeroed at source)
  const bf16x8 ub0 = *reinterpret_cast<const bf16x8*>(&uT[(q0 + qf0 * 16 + lr16) * 32 + g4 * 8]);
  const bf16x8 ub1 = *reinterpret_cast<const bf16x8*>(&uT[(q0 + qf0 * 16 + 16 + lr16) * 32 + g4 * 8]);

  f32x16 acc0, acc1;
  #pragma unroll
  for (int r = 0; r < 16; ++r){ acc0[r] = 0.f; acc1[r] = 0.f; }
  const f32x4 zz = {0.f, 0.f, 0.f, 0.f};

  // ---- per-thread byte offsets (computed once)
  // fsA: LDS chunk d holds src col16 u = (d&7) ^ (c&7) ^ (((c>>3)&1)<<2), c = d>>3
  int fs_src[4];
  #pragma unroll
  for (int it = 0; it < 4; ++it){
    int d = it * 512 + t; int c = d >> 3, s = d & 7;
    int u = s ^ (c & 7) ^ (((c >> 3) & 1) << 2);
    fs_src[it] = c * (HW_SZ * 2) + u * 16;
  }
  // vB: LDS chunk j holds src k-unit u = (j&3) ^ (p&3) ^ ((p>>2)&3), p = j>>2
  int vt_src;
  {
    int j = t & 255; int p = j >> 2, s = j & 3;
    int u = s ^ (p & 3) ^ ((p >> 2) & 3);
    vt_src = p * 64 + u * 16;
  }
  // dgen vB read: row p = pfw*16+lr16, logical unit g4
  int vbr;
  {
    int p = pfw * 16 + lr16;
    vbr = p * 64 + ((g4 ^ (p & 3) ^ ((p >> 2) & 3)) << 4);
  }
  // dgen aT write: q = qf0*16+lr16 (frag0) / +16 (frag1); logical chunk pfw*2+(g4>>1)
  unsigned atw0;
  {
    int qd = qf0 * 16 + lr16;
    int sw = (pfw * 2 + (g4 >> 1)) ^ (qd & 7) ^ (((qd >> 3) & 1) << 2);
    atw0 = qd * 128 + sw * 16 + (g4 & 1) * 8;   // atw1 = atw0 + 2048 (q+16 keeps swz bits)
  }
  // mmain reads: logical chunk = 2ks + g2 -> precompute ks=0 offset, ^ (ks<<5)
  unsigned afo[2], bqo;
  #pragma unroll
  for (int cfi = 0; cfi < 2; ++cfi){
    int crow = cblk * 64 + cfi * 32 + lr32;
    afo[cfi] = crow * 128 + ((g2 ^ (crow & 7) ^ (((crow >> 3) & 1) << 2)) << 4);
  }
  {
    int qrow = qblk * 32 + lr32;
    bqo = qrow * 128 + ((g2 ^ (qrow & 7) ^ (((qrow >> 3) & 1) << 2)) << 4);
  }

  const char* fsb[2] = {(const char*)&fsA[0][0], (const char*)&fsA[1][0]};
  const char* vbb[2] = {(const char*)&vB[0][0], (const char*)&vB[1][0]};
  char* atb = (char*)&aT[0];

  auto stage_fs = [&](unsigned short* dstbase, int p0){
    const char* src = (const char*)fs + p0 * 2;
    #pragma unroll
    for (int it = 0; it < 4; ++it)
      gload16(src + fs_src[it], dstbase + (it * 512 + wv * 64) * 8);
  };
  auto stage_v = [&](unsigned short* dstbase, int p0){
    if (wv < 4)
      gload16((const char*)vT + p0 * 64 + vt_src, dstbase + wv * 512);
  };
  auto dgen = [&](const char* vbB){
    bf16x8 av = *reinterpret_cast<const bf16x8*>(vbB + vbr);
    f32x4 d0 = __builtin_amdgcn_mfma_f32_16x16x32_bf16(av, ub0, zz, 0, 0, 0);
    f32x4 d1 = __builtin_amdgcn_mfma_f32_16x16x32_bf16(av, ub1, zz, 0, 0, 0);
    uint2 pk;
    pk.x = cvtpk(tanh_fast(d0[0]), tanh_fast(d0[1]));
    pk.y = cvtpk(tanh_fast(d0[2]), tanh_fast(d0[3]));
    *reinterpret_cast<uint2*>(atb + atw0) = pk;
    pk.x = cvtpk(tanh_fast(d1[0]), tanh_fast(d1[1]));
    pk.y = cvtpk(tanh_fast(d1[2]), tanh_fast(d1[3]));
    *reinterpret_cast<uint2*>(atb + atw0 + 2048) = pk;
  };
  auto mmain = [&](const char* faB){
    #pragma unroll
    for (int ks = 0; ks < 4; ++ks){
      unsigned kx = (unsigned)(ks << 5);
      bf16x8 b0 = *reinterpret_cast<const bf16x8*>(atb + (bqo ^ kx));
      bf16x8 a0 = *reinterpret_cast<const bf16x8*>(faB + (afo[0] ^ kx));
      bf16x8 a1 = *reinterpret_cast<const bf16x8*>(faB + (afo[1] ^ kx));
      acc0 = __builtin_amdgcn_mfma_f32_32x32x16_bf16(a0, b0, acc0, 0, 0, 0);
      acc1 = __builtin_amdgcn_mfma_f32_32x32x16_bf16(a1, b0, acc1, 0, 0, 0);
    }
  };

  // ---- prologue: chunk 0 into buf 0
  stage_fs(fsA[0], pbase);
  stage_v(vB[0], pbase);
  __syncthreads();

  // ---- main loop: 32 chunks, unrolled x2 (compile-time buffers).
  // Final iteration's prefetch overreads by <=64 cols into adjacent ws buffers (harmless).
  #pragma unroll 1
  for (int k2 = 0; k2 < 16; ++k2){
    {
      const int p0n = pbase + (2 * k2 + 1) * 64;
      stage_fs(fsA[1], p0n);
      stage_v(vB[1], p0n);
      dgen(vbb[0]);
      asm volatile("s_waitcnt lgkmcnt(0)" ::: "memory");
      __builtin_amdgcn_sched_barrier(0);
      __builtin_amdgcn_s_barrier();           // aT visible; DMA still in flight
      mmain(fsb[0]);
      __syncthreads();                        // drains vmcnt (latency already covered)
    }
    {
      const int p0n = pbase + (2 * k2 + 2) * 64;
      stage_fs(fsA[0], p0n);
      stage_v(vB[0], p0n);
      dgen(vbb[1]);
      asm volatile("s_waitcnt lgkmcnt(0)" ::: "memory");
      __builtin_amdgcn_sched_barrier(0);
      __builtin_amdgcn_s_barrier();
      mmain(fsb[1]);
      __syncthreads();
    }
  }

  // ---- store: 32x32 C-layout: col(=q)=lane&31, row(=c)=(reg&3)+8*(reg>>2)+4*(lane>>5)
  const int qcol = q0 + qblk * 32 + lr32;
  #pragma unroll
  for (int r = 0; r < 16; ++r){
    int cr = (r & 3) + 8 * (r >> 2) + 4 * g2;
    out[(cblk * 64 + cr) * HW_SZ + qcol] = acc0[r];
    out[(cblk * 64 + 32 + cr) * HW_SZ + qcol] = acc1[r];
  }
}

// ---------- l2norm(channels) of (part0+part1) + residual + relu (in-place into part0) + stage-2 conv
__global__ void k_norm(float* __restrict__ hat1, float* __restrict__ hat2,
                       const float* __restrict__ pt1, const float* __restrict__ pt2,
                       const float* __restrict__ f1, const float* __restrict__ f2,
                       const float* __restrict__ cw1, const float* __restrict__ cw2,
                       const float* __restrict__ cb1, const float* __restrict__ cb2,
                       float* __restrict__ cv2){
  const int i = blockIdx.z, n = blockIdx.y, t = threadIdx.x;
  const int ql = t & 63, cg = t >> 6;
  const int q = blockIdx.x * 64 + ql;
  float* hat = (i ? hat2 : hat1) + n * C_CH * HW_SZ;
  const float* pt = (i ? pt2 : pt1) + n * C_CH * HW_SZ;
  const float* f = (i ? f2 : f1) + n * C_CH * HW_SZ;
  __shared__ float ws[C_CH];
  __shared__ float red[4][72];
  __shared__ float invs[64];
  ws[t] = (i ? cw2 : cw1)[t];
  __syncthreads();
  float s = 0.f;
  #pragma unroll 8
  for (int c = cg * 64; c < cg * 64 + 64; ++c){
    float h = hat[c * HW_SZ + q] + pt[c * HW_SZ + q];
    s += h * h;
  }
  red[cg][ql] = s; __syncthreads();
  if (t < 64){
    float ss = red[0][t] + red[1][t] + red[2][t] + red[3][t];
    invs[t] = 1.0f / fmaxf(sqrtf(ss), 1e-12f);
  }
  __syncthreads();
  const float inv = invs[ql];
  float ca = 0.f;
  #pragma unroll 8
  for (int c = cg * 64; c < cg * 64 + 64; ++c){
    float h = hat[c * HW_SZ + q] + pt[c * HW_SZ + q];
    float vv = fmaxf(h * inv + f[c * HW_SZ + q], 0.0f);
    hat[c * HW_SZ + q] = vv;  // in-place: only this thread touches [c][q]
    ca += ws[c] * vv;
  }
  red[cg][ql] = ca; __syncthreads();
  if (t < 64){
    float ss = red[0][t] + red[1][t] + red[2][t] + red[3][t] + (i ? cb2[0] : cb1[0]);
    cv2[(i * 2 + n) * HW_SZ + blockIdx.x * 64 + t] = ss;
  }
}

// ---------- final: out_i = pr2_i * fp_i
__global__ void k_final(const float* __restrict__ fp1, const float* __restrict__ fp2,
                        const float* __restrict__ pr2, float* __restrict__ outp){
  const int i = blockIdx.z;
  const int idx4 = (blockIdx.x * 256 + threadIdx.x) * 4;
  const int n = idx4 >> 20;
  const int q = idx4 & (HW_SZ - 1);
  const float* fp = i ? fp2 : fp1;
  float4 vv = *reinterpret_cast<const float4*>(&fp[idx4]);
  float4 pp = *reinterpret_cast<const float4*>(&pr2[(i * 2 + n) * HW_SZ + q]);
  float4 o; o.x = vv.x * pp.x; o.y = vv.y * pp.y; o.z = vv.z * pp.z; o.w = vv.w * pp.w;
  *reinterpret_cast<float4*>(&outp[i * (C_CH * HW_SZ * N_B) + idx4]) = o;
}

extern "C" void kernel_launch(void* const* d_in, const int* in_sizes, int n_in,
                              void* d_out, int out_size, void* d_ws, size_t ws_size,
                              hipStream_t stream){
  const float* f1  = (const float*)d_in[0];
  const float* f2  = (const float*)d_in[1];
  const float* pw1 = (const float*)d_in[2];
  const float* pb1 = (const float*)d_in[3];
  const float* pw2 = (const float*)d_in[4];
  const float* pb2 = (const float*)d_in[5];
  const float* cw1 = (const float*)d_in[6];
  const float* cb1 = (const float*)d_in[7];
  const float* cw2 = (const float*)d_in[8];
  const float* cb2 = (const float*)d_in[9];
  float* ws = (float*)d_ws;
  // layout (float offsets): HAT = part0 (doubles as FP), PT = part1
  float* HAT1 = ws;                                        // 2,097,152 floats each
  float* HAT2 = ws + 2097152;
  float* PT1  = ws + 4194304;
  float* PT2  = ws + 6291456;
  unsigned short* FS1 = (unsigned short*)(ws + 8388608);   // bf16 [C][HW] per n
  unsigned short* FS2 = (unsigned short*)(ws + 9437184);
  unsigned short* CLT1 = (unsigned short*)(ws + 10485760); // bf16 [HW][32] per n
  unsigned short* CLT2 = (unsigned short*)(ws + 10616832);
  float* CV1  = ws + 10747904;
  float* PR1  = ws + 10764288;
  float* CV2  = ws + 10780672;
  float* PR2  = ws + 10797056;                             // end 10,813,440 floats ~= 43.3 MiB
  float* outp = (float*)d_out;

  k_conv1   <<<dim3(64, 2, 2), 256, 0, stream>>>(f1, f2, cw1, cw2, cb1, cb2, CV1);
  k_softmax <<<4, 256, 0, stream>>>(CV1, PR1);
  k_scale_cl<<<dim3(64, 2, 2), 256, 0, stream>>>(f1, f2, PR1, pw1, pw2, pb1, pb2,
                                                 FS1, FS2, CLT1, CLT2);
  k_hat     <<<512, 512, 0, stream>>>(FS1, FS2, CLT1, CLT2, HAT1, HAT2, PT1, PT2);
  k_norm    <<<dim3(64, 2, 2), 256, 0, stream>>>(HAT1, HAT2, PT1, PT2, f1, f2,
                                                 cw1, cw2, cb1, cb2, CV2);
  k_softmax <<<4, 256, 0, stream>>>(CV2, PR2);
  k_final   <<<dim3(2048, 1, 2), 256, 0, stream>>>(HAT1, HAT2, PR2, outp);
}